// Round 9
// baseline (1290.540 us; speedup 1.0000x reference)
//
#include <hip/hip_runtime.h>
#include <math.h>

#define HID 128

typedef __attribute__((ext_vector_type(8))) short bf16x8;
typedef __attribute__((ext_vector_type(4))) float f32x4;

__device__ __forceinline__ float silu_f(float v) {
    return v * __builtin_amdgcn_rcpf(1.0f + __expf(-v));
}
__device__ __forceinline__ float sigmoid_f(float v) {
    return __builtin_amdgcn_rcpf(1.0f + __expf(-v));
}
__device__ __forceinline__ unsigned short bf16hi(float f) {
    return (unsigned short)(__float_as_uint(f) >> 16);
}
__device__ __forceinline__ float bf16tof(unsigned short u) {
    return __uint_as_float(((unsigned int)u) << 16);
}

// ---------- CSR / sort-by-row (rows static across layers; built once per call) ----------
__global__ void k_cnt(const int* __restrict__ rows, int* __restrict__ cnti, int E) {
    int i = blockIdx.x * 256 + threadIdx.x;
    if (i < E) atomicAdd(&cnti[rows[i]], 1);
}

// single-block exclusive scan over N counts -> base
__global__ void k_scan(const int* __restrict__ cnti, int* __restrict__ base, int N) {
    __shared__ int part[256];
    int t = threadIdx.x;
    int chunk = (N + 255) / 256;
    int lo = t * chunk, hi = lo + chunk < N ? lo + chunk : N;
    int s = 0;
    for (int i = lo; i < hi; ++i) s += cnti[i];
    part[t] = s;
    __syncthreads();
    for (int off = 1; off < 256; off <<= 1) {
        int v = (t >= off) ? part[t - off] : 0;
        __syncthreads();
        part[t] += v;
        __syncthreads();
    }
    int run = (t == 0) ? 0 : part[t - 1];
    for (int i = lo; i < hi; ++i) { base[i] = run; run += cnti[i]; }
}

__global__ void k_scatter(const int* __restrict__ rows, const int* __restrict__ cols,
                          const float* __restrict__ eattr,
                          const int* __restrict__ base, int* __restrict__ fill,
                          int* __restrict__ srow, int* __restrict__ scol,
                          float* __restrict__ sea, int E) {
    int e = blockIdx.x * 256 + threadIdx.x;
    if (e >= E) return;
    int r = rows[e];
    int pos = base[r] + atomicAdd(&fill[r], 1);
    srow[pos] = r;
    scol[pos] = cols[e];
    sea[pos * 2 + 0] = eattr[(size_t)e * 2 + 0];
    sea[pos * 2 + 1] = eattr[(size_t)e * 2 + 1];
}

__global__ void k_embed(const float* __restrict__ hin, const float* __restrict__ w,
                        const float* __restrict__ b, float* __restrict__ hout, int N) {
    int idx = blockIdx.x * 256 + threadIdx.x;
    if (idx >= N * HID) return;
    int n = idx >> 7, j = idx & 127;
    float s = b[j];
    const float* hr = &hin[n * 6];
#pragma unroll
    for (int k = 0; k < 6; ++k) s += hr[k] * w[k * HID + j];
    hout[idx] = s;
}

// pack weights for MFMA (hi/lo split): s-block = [hi 1024 | lo 1024], entry n*8 + (k&7)
__global__ void k_pack_w(const float* __restrict__ ew2, const float* __restrict__ cw1,
                         unsigned short* __restrict__ w2p, unsigned short* __restrict__ c1p) {
    int idx = blockIdx.x * 256 + threadIdx.x;
    if (idx >= 4 * 32768) return;
    int l = idx >> 15, r = idx & 32767;
    const float* src;
    unsigned short* dst;
    int k, n;
    if (r < 16384) {
        k = r >> 7; n = r & 127;
        src = ew2 + (size_t)l * 16384 + k * 128 + n;
        dst = w2p + (size_t)l * 32768;
    } else {
        int rr = r - 16384; k = rr >> 7; n = rr & 127;
        src = cw1 + (size_t)l * 16384 + k * 128 + n;
        dst = c1p + (size_t)l * 32768;
    }
    float f = *src;
    unsigned short hi = bf16hi(f);
    float rem = f - bf16tof(hi);
    int s = k >> 3;
    int b = s * 2048 + n * 8 + (k & 7);
    dst[b] = hi;
    dst[b + 1024] = bf16hi(rem);
}

// per-node GEMM1 hoist: Hrow = h @ W[0:128] + eb1, Hcol = h @ W[128:256]  (fp32, exact)
// (used once after embedding; subsequent layers fuse this into k_node)
__global__ __launch_bounds__(256, 2) void k_hpre(
    const float* __restrict__ h, const float* __restrict__ w,
    const float* __restrict__ eb1,
    float* __restrict__ Hrow, float* __restrict__ Hcol, int N)
{
    __shared__ __align__(16) float BH[64][132];
    const int t = threadIdx.x;
    const int tx = t & 15, ty = t >> 4;
    const int n0 = blockIdx.x * 64;

    for (int idx = t; idx < 64 * 32; idx += 256) {
        int r = idx >> 5, c4 = idx & 31;
        int n = n0 + r;
        float4 v0 = make_float4(0.f, 0.f, 0.f, 0.f);
        if (n < N) v0 = *(const float4*)&h[(size_t)n * HID + c4 * 4];
        *(float4*)&BH[r][c4 * 4] = v0;
    }
    __syncthreads();

    float ar[4][8], ac[4][8];
#pragma unroll
    for (int i = 0; i < 4; ++i)
#pragma unroll
        for (int j = 0; j < 8; ++j) { ar[i][j] = 0.f; ac[i][j] = 0.f; }

    const float* wr = &w[tx * 8];
    const float* wc = &w[128 * HID + tx * 8];
#pragma unroll 4
    for (int k = 0; k < HID; ++k) {
        float4 r0 = *(const float4*)&wr[k * HID];
        float4 r1 = *(const float4*)&wr[k * HID + 4];
        float4 c0 = *(const float4*)&wc[k * HID];
        float4 c1 = *(const float4*)&wc[k * HID + 4];
        float rv[8] = {r0.x, r0.y, r0.z, r0.w, r1.x, r1.y, r1.z, r1.w};
        float cv[8] = {c0.x, c0.y, c0.z, c0.w, c1.x, c1.y, c1.z, c1.w};
        float av[4];
#pragma unroll
        for (int i = 0; i < 4; ++i) av[i] = BH[ty * 4 + i][k];
#pragma unroll
        for (int i = 0; i < 4; ++i)
#pragma unroll
            for (int j = 0; j < 8; ++j) {
                ar[i][j] += av[i] * rv[j];
                ac[i][j] += av[i] * cv[j];
            }
    }
#pragma unroll
    for (int i = 0; i < 4; ++i) {
        int n = n0 + ty * 4 + i;
        if (n < N) {
#pragma unroll
            for (int j = 0; j < 8; ++j) {
                Hrow[(size_t)n * HID + tx * 8 + j] = ar[i][j] + eb1[tx * 8 + j];
                Hcol[(size_t)n * HID + tx * 8 + j] = ac[i][j];
            }
        }
    }
}

// MFMA edge kernel over SORTED edges: 32 edges/block, 4 waves = 2 groups x 2
// channel-half waves. Each wave computes 64 of the 128 output channels for its
// group's 16 edges -> accumulators/fragments halve (16 regs each), no spill.
// Shared [16][128] split-bf16 tile per group carries e_act then m; gate
// partials exchanged via LDS; 3 barriers. All fragment arrays use STATIC
// unrolled indices only. launch_bounds(256,6): 85-VGPR cap (spill-free at
// ~40 live), 6 blocks/CU = 75% occupancy.
__global__ __launch_bounds__(256, 6) void k_edge_mfma(
    const float* __restrict__ Hrow, const float* __restrict__ Hcol,
    const float* __restrict__ x,
    const int* __restrict__ srow, const int* __restrict__ scol,
    const float* __restrict__ sea,
    const float* __restrict__ ew1_tail,
    const unsigned short* __restrict__ w2p, const float* __restrict__ eb2,
    const float* __restrict__ aw, const float* __restrict__ ab,
    const unsigned short* __restrict__ c1p, const float* __restrict__ cb1,
    const float* __restrict__ cw2,
    float* __restrict__ aggh, float* __restrict__ aggx, int E)
{
    __shared__ __align__(16) unsigned short tHi[2][16][136];
    __shared__ __align__(16) unsigned short tLo[2][16][136];
    __shared__ float sGate[2][2][16];
    __shared__ float sCD[32][4];
    __shared__ float sEA[32][2];
    __shared__ int sRow[32], sCol[32];

    const int t = threadIdx.x;
    const int wv = t >> 6, lane = t & 63;
    const int grp = wv >> 1, hf = wv & 1;
    const int quad = lane >> 4, ln = lane & 15;
    const int e0 = blockIdx.x * 32;

    // metadata: each wave writes its group's 16 edges (both waves write identical
    // values to the same addresses -> race-free by value; wave-internal ordering
    // makes them visible to this wave's own reads without a barrier)
    if (lane < 16) {
        int eg = e0 + grp * 16 + lane;
        int ec = eg < E ? eg : E - 1;
        int r = srow[ec], c = scol[ec];
        sRow[grp * 16 + lane] = r; sCol[grp * 16 + lane] = c;
        float dx = x[r * 3 + 0] - x[c * 3 + 0];
        float dy = x[r * 3 + 1] - x[c * 3 + 1];
        float dz = x[r * 3 + 2] - x[c * 3 + 2];
        sCD[grp * 16 + lane][0] = dx;
        sCD[grp * 16 + lane][1] = dy;
        sCD[grp * 16 + lane][2] = dz;
        sCD[grp * 16 + lane][3] = dx * dx + dy * dy + dz * dz;
        sEA[grp * 16 + lane][0] = sea[(size_t)ec * 2 + 0];
        sEA[grp * 16 + lane][1] = sea[(size_t)ec * 2 + 1];
    }

    const int eM = grp * 16 + ln;
    const int rn = sRow[eM], cn = sCol[eM];
    const float rad = sCD[eM][3], ea0 = sEA[eM][0], ea1 = sEA[eM][1];

    // ---- phase 1: e_act (fused GEMM1) for this wave's channel half; edge = ln
#pragma unroll
    for (int kk = 0; kk < 2; ++kk) {
        const int kc = hf * 2 + kk;
        const int fb = kc * 32 + quad * 8;
        f32x4 a0 = *(const f32x4*)(Hrow + (size_t)rn * HID + fb);
        f32x4 a1 = *(const f32x4*)(Hrow + (size_t)rn * HID + fb + 4);
        f32x4 c0 = *(const f32x4*)(Hcol + (size_t)cn * HID + fb);
        f32x4 c1 = *(const f32x4*)(Hcol + (size_t)cn * HID + fb + 4);
        f32x4 w60 = *(const f32x4*)(ew1_tail + fb);
        f32x4 w61 = *(const f32x4*)(ew1_tail + fb + 4);
        f32x4 w70 = *(const f32x4*)(ew1_tail + 128 + fb);
        f32x4 w71 = *(const f32x4*)(ew1_tail + 128 + fb + 4);
        f32x4 w80 = *(const f32x4*)(ew1_tail + 256 + fb);
        f32x4 w81 = *(const f32x4*)(ew1_tail + 256 + fb + 4);
        bf16x8 ahi, alo;
#pragma unroll
        for (int j = 0; j < 4; ++j) {
            float s0 = a0[j] + c0[j] + rad * w60[j] + ea0 * w70[j] + ea1 * w80[j];
            float s1 = a1[j] + c1[j] + rad * w61[j] + ea0 * w71[j] + ea1 * w81[j];
            s0 = silu_f(s0);
            s1 = silu_f(s1);
            unsigned short h0 = bf16hi(s0), h1 = bf16hi(s1);
            ahi[j] = (short)h0;
            ahi[j + 4] = (short)h1;
            alo[j] = (short)bf16hi(s0 - bf16tof(h0));
            alo[j + 4] = (short)bf16hi(s1 - bf16tof(h1));
        }
        *(bf16x8*)&tHi[grp][ln][fb] = ahi;
        *(bf16x8*)&tLo[grp][ln][fb] = alo;
    }
    __syncthreads();   // barrier A: e_act tile complete

    // ---- read full-K GEMM2 A-fragments (static indices)
    bf16x8 g1hi[4], g1lo[4];
#pragma unroll
    for (int kc = 0; kc < 4; ++kc) {
        g1hi[kc] = *(const bf16x8*)&tHi[grp][ln][kc * 32 + quad * 8];
        g1lo[kc] = *(const bf16x8*)&tLo[grp][ln][kc * 32 + quad * 8];
    }

    // ---- GEMM2: this wave's 4 output tiles (channels hf*64 .. hf*64+63)
    f32x4 acc2[4];
#pragma unroll
    for (int i = 0; i < 4; ++i) acc2[i] = (f32x4){0.f, 0.f, 0.f, 0.f};
#pragma unroll
    for (int t8l = 0; t8l < 4; ++t8l) {
        const int t8 = hf * 4 + t8l;
        const unsigned short* bg = w2p + quad * 2048 + ln * 8 + t8 * 128;
#pragma unroll
        for (int kc = 0; kc < 4; ++kc) {
            bf16x8 bhi = *(const bf16x8*)(bg + kc * 8192);
            bf16x8 blo = *(const bf16x8*)(bg + kc * 8192 + 1024);
            acc2[t8l] = __builtin_amdgcn_mfma_f32_16x16x32_bf16(g1hi[kc], bhi, acc2[t8l], 0, 0, 0);
            acc2[t8l] = __builtin_amdgcn_mfma_f32_16x16x32_bf16(g1lo[kc], bhi, acc2[t8l], 0, 0, 0);
            acc2[t8l] = __builtin_amdgcn_mfma_f32_16x16x32_bf16(g1hi[kc], blo, acc2[t8l], 0, 0, 0);
        }
    }

    // ---- silu + gate partial over this half's channels
    float pr[4] = {0.f, 0.f, 0.f, 0.f};
#pragma unroll
    for (int t8l = 0; t8l < 4; ++t8l) {
        int n = (hf * 4 + t8l) * 16 + ln;
        float bb = eb2[n], awn = aw[n];
#pragma unroll
        for (int r = 0; r < 4; ++r) {
            float v = silu_f(acc2[t8l][r] + bb);
            acc2[t8l][r] = v;
            pr[r] += v * awn;
        }
    }
#pragma unroll
    for (int r = 0; r < 4; ++r) {
        float p = pr[r];
        p += __shfl_xor(p, 1);
        p += __shfl_xor(p, 2);
        p += __shfl_xor(p, 4);
        p += __shfl_xor(p, 8);
        pr[r] = p;   // partial gate dot for edge quad*4+r
    }
    if (ln == 0) {
#pragma unroll
        for (int r = 0; r < 4; ++r) sGate[grp][hf][quad * 4 + r] = pr[r];
    }
    __syncthreads();   // barrier B: gate partials ready; all e_act reads done

    float gate[4];
    {
        float ab0 = ab[0];
#pragma unroll
        for (int r = 0; r < 4; ++r)
            gate[r] = sigmoid_f(sGate[grp][0][quad * 4 + r] +
                                sGate[grp][1][quad * 4 + r] + ab0);
    }

    // ---- gate + write m (this half) into the tile (overwrites own e_act half)
#pragma unroll
    for (int t8l = 0; t8l < 4; ++t8l) {
        int n = (hf * 4 + t8l) * 16 + ln;
#pragma unroll
        for (int r = 0; r < 4; ++r) {
            float v = acc2[t8l][r] * gate[r];
            acc2[t8l][r] = v;                 // keep gated m (fp32) for agg_h
            unsigned short hi = bf16hi(v);
            float rem = v - bf16tof(hi);
            tHi[grp][quad * 4 + r][n] = hi;
            tLo[grp][quad * 4 + r][n] = bf16hi(rem);
        }
    }

    // ---- agg_h: run-segmented reduction (this half's channels, exact fp32)
    {
        int i = 0;
        while (i < 16) {
            int node = sRow[grp * 16 + i];
            int j = i + 1;
            while (j < 16 && sRow[grp * 16 + j] == node) ++j;
#pragma unroll
            for (int t8l = 0; t8l < 4; ++t8l) {
                float s = 0.f;
#pragma unroll
                for (int r = 0; r < 4; ++r) {
                    int el = quad * 4 + r;
                    bool ok = (el >= i) && (el < j) && (e0 + grp * 16 + el < E);
                    s += ok ? acc2[t8l][r] : 0.f;
                }
                s += __shfl_xor(s, 16);
                s += __shfl_xor(s, 32);
                if (quad == (t8l & 3))
                    atomicAdd(&aggh[(size_t)node * HID + (hf * 4 + t8l) * 16 + ln], s);
            }
            i = j;
        }
    }
    __syncthreads();   // barrier C: m tile complete

    // ---- GEMM3 (this wave's half of output channels; full-K m fragments)
    bf16x8 g3hi[4], g3lo[4];
#pragma unroll
    for (int kc = 0; kc < 4; ++kc) {
        g3hi[kc] = *(const bf16x8*)&tHi[grp][ln][kc * 32 + quad * 8];
        g3lo[kc] = *(const bf16x8*)&tLo[grp][ln][kc * 32 + quad * 8];
    }
    f32x4 acc3[4];
#pragma unroll
    for (int i = 0; i < 4; ++i) acc3[i] = (f32x4){0.f, 0.f, 0.f, 0.f};
#pragma unroll
    for (int t8l = 0; t8l < 4; ++t8l) {
        const int t8 = hf * 4 + t8l;
        const unsigned short* bg = c1p + quad * 2048 + ln * 8 + t8 * 128;
#pragma unroll
        for (int kc = 0; kc < 4; ++kc) {
            bf16x8 bhi = *(const bf16x8*)(bg + kc * 8192);
            bf16x8 blo = *(const bf16x8*)(bg + kc * 8192 + 1024);
            acc3[t8l] = __builtin_amdgcn_mfma_f32_16x16x32_bf16(g3hi[kc], bhi, acc3[t8l], 0, 0, 0);
            acc3[t8l] = __builtin_amdgcn_mfma_f32_16x16x32_bf16(g3lo[kc], bhi, acc3[t8l], 0, 0, 0);
            acc3[t8l] = __builtin_amdgcn_mfma_f32_16x16x32_bf16(g3hi[kc], blo, acc3[t8l], 0, 0, 0);
        }
    }
    {
        float pr3[4] = {0.f, 0.f, 0.f, 0.f};
#pragma unroll
        for (int t8l = 0; t8l < 4; ++t8l) {
            int n = (hf * 4 + t8l) * 16 + ln;
            float bb = cb1[n], cwn = cw2[n];
#pragma unroll
            for (int r = 0; r < 4; ++r) {
                float u = silu_f(acc3[t8l][r] + bb);
                pr3[r] += u * cwn;
            }
        }
#pragma unroll
        for (int r = 0; r < 4; ++r) {
            float p = pr3[r];
            p += __shfl_xor(p, 1);
            p += __shfl_xor(p, 2);
            p += __shfl_xor(p, 4);
            p += __shfl_xor(p, 8);
            pr3[r] = p;   // partial w (this half); halves sum via atomics
        }
        // ---- agg_x: run-segmented reduction (partial w; both waves atomicAdd)
        int i = 0;
        while (i < 16) {
            int node = sRow[grp * 16 + i];
            int j = i + 1;
            while (j < 16 && sRow[grp * 16 + j] == node) ++j;
            float s = 0.f;
            if (ln < 3) {
#pragma unroll
                for (int r = 0; r < 4; ++r) {
                    int el = quad * 4 + r;
                    int m = grp * 16 + el;
                    bool ok = (el >= i) && (el < j) && (e0 + m < E);
                    s += ok ? sCD[m][ln] * pr3[r] : 0.f;
                }
            }
            s += __shfl_xor(s, 16);
            s += __shfl_xor(s, 32);
            if (quad == 0 && ln < 3)
                atomicAdd(&aggx[node * 3 + ln], s);
            i = j;
        }
    }
}

// 16 nodes per block, 256 threads (fp32); each ty owns one node. Zeroes
// aggh/aggx after reading (replaces per-layer memsets). Optionally fuses next
// layer's Hrow/Hcol precompute (eb1 folded into Hrow). 625 blocks.
__global__ __launch_bounds__(256, 4) void k_node(
    float* __restrict__ h, float* __restrict__ aggh,
    float* __restrict__ aggx, const int* __restrict__ cnti,
    float* __restrict__ x, float* __restrict__ vel,
    const float* __restrict__ vw1, const float* __restrict__ vb1,
    const float* __restrict__ vw2, const float* __restrict__ vb2,
    const float* __restrict__ nw1, const float* __restrict__ nb1,
    const float* __restrict__ nw2, const float* __restrict__ nb2,
    int N,
    const float* __restrict__ ew1n, const float* __restrict__ eb1n,
    float* __restrict__ Hrow, float* __restrict__ Hcol)
{
    __shared__ __align__(16) float BH[16][132];
    __shared__ __align__(16) float BG[16][132];
    const int t = threadIdx.x;
    const int tx = t & 15, ty = t >> 4;
    const int n0 = blockIdx.x * 16;
    const int myn = n0 + ty;
    const bool valid = myn < N;

    for (int idx = t; idx < 16 * 32; idx += 256) {
        int r = idx >> 5, c4 = idx & 31;
        int n = n0 + r;
        float4 v0 = make_float4(0.f, 0.f, 0.f, 0.f), v1 = v0;
        if (n < N) {
            v0 = *(const float4*)&h[(size_t)n * HID + c4 * 4];
            v1 = *(const float4*)&aggh[(size_t)n * HID + c4 * 4];
            *(float4*)&aggh[(size_t)n * HID + c4 * 4] =
                make_float4(0.f, 0.f, 0.f, 0.f);   // zero for next layer
        }
        *(float4*)&BH[r][c4 * 4] = v0;
        *(float4*)&BG[r][c4 * 4] = v1;
    }
    __syncthreads();

    {
        float acc[8];
#pragma unroll
        for (int j = 0; j < 8; ++j) acc[j] = 0.f;
        const float* wp = &vw1[tx * 8];
#pragma unroll 4
        for (int k = 0; k < HID; ++k) {
            float4 w0 = *(const float4*)&wp[k * HID];
            float4 w1v = *(const float4*)&wp[k * HID + 4];
            float wv[8] = {w0.x, w0.y, w0.z, w0.w, w1v.x, w1v.y, w1v.z, w1v.w};
            float av = BH[ty][k];
#pragma unroll
            for (int j = 0; j < 8; ++j) acc[j] += av * wv[j];
        }
        float bb[8], w2v[8];
#pragma unroll
        for (int j = 0; j < 8; ++j) { bb[j] = vb1[tx * 8 + j]; w2v[j] = vw2[tx * 8 + j]; }
        float vb20 = vb2[0];
        float p = 0.f;
#pragma unroll
        for (int j = 0; j < 8; ++j) p += silu_f(acc[j] + bb[j]) * w2v[j];
        p += __shfl_xor(p, 1);
        p += __shfl_xor(p, 2);
        p += __shfl_xor(p, 4);
        p += __shfl_xor(p, 8);
        float vs = p + vb20;
        if (tx == 0 && valid) {
            float cc = fmaxf((float)cnti[myn], 1.0f);
#pragma unroll
            for (int d = 0; d < 3; ++d) {
                float vn = vs * vel[myn * 3 + d];
                float xn = x[myn * 3 + d] + aggx[myn * 3 + d] / cc + vn;
                vel[myn * 3 + d] = vn;
                x[myn * 3 + d] = xn;
                aggx[myn * 3 + d] = 0.f;   // zero for next layer
            }
        }
    }

    float acc2[8];
#pragma unroll
    for (int j = 0; j < 8; ++j) acc2[j] = 0.f;
    {
        const float* wp = &nw1[tx * 8];
#pragma unroll 4
        for (int k = 0; k < HID; ++k) {
            float4 w0 = *(const float4*)&wp[k * HID];
            float4 w1v = *(const float4*)&wp[k * HID + 4];
            float wv[8] = {w0.x, w0.y, w0.z, w0.w, w1v.x, w1v.y, w1v.z, w1v.w};
            float av = BH[ty][k];
#pragma unroll
            for (int j = 0; j < 8; ++j) acc2[j] += av * wv[j];
        }
        const float* wp2 = &nw1[128 * HID + tx * 8];
#pragma unroll 4
        for (int k = 0; k < HID; ++k) {
            float4 w0 = *(const float4*)&wp2[k * HID];
            float4 w1v = *(const float4*)&wp2[k * HID + 4];
            float wv[8] = {w0.x, w0.y, w0.z, w0.w, w1v.x, w1v.y, w1v.z, w1v.w};
            float av = BG[ty][k];
#pragma unroll
            for (int j = 0; j < 8; ++j) acc2[j] += av * wv[j];
        }
    }
    __syncthreads();
    {
        float bb[8];
#pragma unroll
        for (int j = 0; j < 8; ++j) bb[j] = nb1[tx * 8 + j];
#pragma unroll
        for (int j = 0; j < 8; ++j)
            BH[ty][tx * 8 + j] = silu_f(acc2[j] + bb[j]);
    }
    __syncthreads();
    float acc3[8];
#pragma unroll
    for (int j = 0; j < 8; ++j) acc3[j] = 0.f;
    {
        const float* wp = &nw2[tx * 8];
#pragma unroll 4
        for (int k = 0; k < HID; ++k) {
            float4 w0 = *(const float4*)&wp[k * HID];
            float4 w1v = *(const float4*)&wp[k * HID + 4];
            float wv[8] = {w0.x, w0.y, w0.z, w0.w, w1v.x, w1v.y, w1v.z, w1v.w};
            float av = BH[ty][k];
#pragma unroll
            for (int j = 0; j < 8; ++j) acc3[j] += av * wv[j];
        }
    }
    float hv[8];
    {
        float bb[8];
#pragma unroll
        for (int j = 0; j < 8; ++j) bb[j] = nb2[tx * 8 + j];
#pragma unroll
        for (int j = 0; j < 8; ++j) hv[j] = acc3[j] + bb[j];
        if (valid) {
#pragma unroll
            for (int j = 0; j < 8; ++j)
                h[(size_t)myn * HID + tx * 8 + j] = hv[j];
        }
    }

    if (ew1n == nullptr) return;

    // ---- fused hpre for next layer: Hrow/Hcol = h_new @ ew1n[0:128 / 128:256]
    __syncthreads();   // all reads of BH (acc3 GEMM) complete
#pragma unroll
    for (int j = 0; j < 8; ++j)
        BH[ty][tx * 8 + j] = hv[j];
    __syncthreads();

    float ar[8], ac[8];
#pragma unroll
    for (int j = 0; j < 8; ++j) { ar[j] = 0.f; ac[j] = 0.f; }
    const float* wr = &ew1n[tx * 8];
    const float* wc = &ew1n[128 * HID + tx * 8];
#pragma unroll 4
    for (int k = 0; k < HID; ++k) {
        float4 r0 = *(const float4*)&wr[k * HID];
        float4 r1 = *(const float4*)&wr[k * HID + 4];
        float4 c0 = *(const float4*)&wc[k * HID];
        float4 c1 = *(const float4*)&wc[k * HID + 4];
        float rv[8] = {r0.x, r0.y, r0.z, r0.w, r1.x, r1.y, r1.z, r1.w};
        float cv[8] = {c0.x, c0.y, c0.z, c0.w, c1.x, c1.y, c1.z, c1.w};
        float av = BH[ty][k];
#pragma unroll
        for (int j = 0; j < 8; ++j) {
            ar[j] += av * rv[j];
            ac[j] += av * cv[j];
        }
    }
    if (valid) {
#pragma unroll
        for (int j = 0; j < 8; ++j) {
            Hrow[(size_t)myn * HID + tx * 8 + j] = ar[j] + eb1n[tx * 8 + j];
            Hcol[(size_t)myn * HID + tx * 8 + j] = ac[j];
        }
    }
}

__global__ void k_proj(const float* __restrict__ h, const float* __restrict__ pw,
                       const float* __restrict__ pb, float* __restrict__ out, int N) {
    int idx = blockIdx.x * 256 + threadIdx.x;
    if (idx >= N * 3) return;
    int n = idx / 3, p = idx % 3;
    float s = pb[p];
    const float* hr = &h[(size_t)n * HID];
#pragma unroll 8
    for (int k = 0; k < HID; ++k) s += hr[k] * pw[k * 3 + p];
    out[idx] = s;
}

extern "C" void kernel_launch(void* const* d_in, const int* in_sizes, int n_in,
                              void* d_out, int out_size, void* d_ws, size_t ws_size,
                              hipStream_t stream)
{
    const float* h_in  = (const float*)d_in[0];
    const float* x_in  = (const float*)d_in[1];
    const float* v_in  = (const float*)d_in[2];
    const float* eattr = (const float*)d_in[3];
    const int*   edges = (const int*)d_in[4];
    const float* emb_w = (const float*)d_in[5];
    const float* emb_b = (const float*)d_in[6];
    const float* ew1   = (const float*)d_in[7];
    const float* eb1   = (const float*)d_in[8];
    const float* ew2   = (const float*)d_in[9];
    const float* eb2   = (const float*)d_in[10];
    const float* aw    = (const float*)d_in[11];
    const float* ab    = (const float*)d_in[12];
    const float* nw1   = (const float*)d_in[13];
    const float* nb1   = (const float*)d_in[14];
    const float* nw2   = (const float*)d_in[15];
    const float* nb2   = (const float*)d_in[16];
    const float* cw1   = (const float*)d_in[17];
    const float* cb1   = (const float*)d_in[18];
    const float* cw2   = (const float*)d_in[19];
    const float* vw1   = (const float*)d_in[20];
    const float* vb1   = (const float*)d_in[21];
    const float* vw2   = (const float*)d_in[22];
    const float* vb2   = (const float*)d_in[23];
    const float* pw    = (const float*)d_in[24];
    const float* pb    = (const float*)d_in[25];

    const int N = in_sizes[0] / 6;
    const int E = in_sizes[4] / 2;
    const int* rows = edges;
    const int* cols = edges + E;

    float* ws   = (float*)d_ws;
    float* hbuf = ws;  ws += (size_t)N * HID;
    float* aggh = ws;  ws += (size_t)N * HID;
    float* aggx = ws;  ws += (size_t)N * 3;
    float* xb   = ws;  ws += (size_t)N * 3;
    float* vb   = ws;  ws += (size_t)N * 3;
    float* sea  = ws;  ws += (size_t)E * 2;
    float* Hrow = ws;  ws += (size_t)N * HID;
    float* Hcol = ws;  ws += (size_t)N * HID;
    int* wi = (int*)ws;
    int* cnti = wi;  wi += N;
    int* basei = wi; wi += N;
    int* fill = wi;  wi += N;
    int* srow = wi;  wi += E;
    int* scol = wi;  wi += E;
    unsigned short* us = (unsigned short*)wi;
    unsigned short* w2p = us;  us += 4 * 32768;
    unsigned short* c1p = us;  us += 4 * 32768;
    float* outp = (float*)d_out;

    hipMemcpyAsync(xb, x_in, (size_t)N * 3 * sizeof(float), hipMemcpyDeviceToDevice, stream);
    hipMemcpyAsync(vb, v_in, (size_t)N * 3 * sizeof(float), hipMemcpyDeviceToDevice, stream);
    hipMemsetAsync(cnti, 0, 2 * N * sizeof(int), stream);  // cnti+basei; fill separate
    hipMemsetAsync(fill, 0, N * sizeof(int), stream);
    hipMemsetAsync(aggh, 0, (size_t)N * HID * sizeof(float), stream);  // layer 0 only;
    hipMemsetAsync(aggx, 0, (size_t)N * 3 * sizeof(float), stream);    // k_node re-zeroes
    k_cnt<<<(E + 255) / 256, 256, 0, stream>>>(rows, cnti, E);
    k_scan<<<1, 256, 0, stream>>>(cnti, basei, N);
    k_scatter<<<(E + 255) / 256, 256, 0, stream>>>(rows, cols, eattr, basei, fill,
                                                   srow, scol, sea, E);
    k_pack_w<<<(4 * 32768 + 255) / 256, 256, 0, stream>>>(ew2, cw1, w2p, c1p);
    k_embed<<<(N * HID + 255) / 256, 256, 0, stream>>>(h_in, emb_w, emb_b, hbuf, N);
    k_hpre<<<(N + 63) / 64, 256, 0, stream>>>(hbuf, ew1, eb1, Hrow, Hcol, N);

    for (int l = 0; l < 4; ++l) {
        k_edge_mfma<<<(E + 31) / 32, 256, 0, stream>>>(
            Hrow, Hcol, xb, srow, scol, sea,
            ew1 + (size_t)l * 33152 + 256 * HID,
            w2p + (size_t)l * 32768, eb2 + l * HID,
            aw + l * HID, ab + l,
            c1p + (size_t)l * 32768, cb1 + l * HID, cw2 + l * HID,
            aggh, aggx, E);
        k_node<<<(N + 15) / 16, 256, 0, stream>>>(
            hbuf, aggh, aggx, cnti, xb, vb,
            vw1 + (size_t)l * HID * HID, vb1 + l * HID, vw2 + l * HID, vb2 + l,
            nw1 + (size_t)l * 2 * HID * HID, nb1 + l * HID,
            nw2 + (size_t)l * HID * HID, nb2 + l * HID, N,
            (l < 3) ? (ew1 + (size_t)(l + 1) * 33152) : nullptr,
            (l < 3) ? (eb1 + (size_t)(l + 1) * HID) : nullptr, Hrow, Hcol);
    }
    k_proj<<<(N * 3 + 255) / 256, 256, 0, stream>>>(hbuf, pw, pb, outp, N);
    hipMemcpyAsync(outp + (size_t)N * 3, xb, (size_t)N * 3 * sizeof(float), hipMemcpyDeviceToDevice, stream);
    hipMemcpyAsync(outp + (size_t)N * 6, vb, (size_t)N * 3 * sizeof(float), hipMemcpyDeviceToDevice, stream);
}

// Round 11
// 1161.876 us; speedup vs baseline: 1.1107x; 1.1107x over previous
//
#include <hip/hip_runtime.h>
#include <math.h>

#define HID 128

typedef __attribute__((ext_vector_type(8))) short bf16x8;
typedef __attribute__((ext_vector_type(4))) float f32x4;

__device__ __forceinline__ float silu_f(float v) {
    return v * __builtin_amdgcn_rcpf(1.0f + __expf(-v));
}
__device__ __forceinline__ float sigmoid_f(float v) {
    return __builtin_amdgcn_rcpf(1.0f + __expf(-v));
}
__device__ __forceinline__ unsigned short bf16hi(float f) {
    return (unsigned short)(__float_as_uint(f) >> 16);
}
__device__ __forceinline__ float bf16tof(unsigned short u) {
    return __uint_as_float(((unsigned int)u) << 16);
}

// ---------- CSR / sort-by-row (rows static across layers; built once per call) ----------
__global__ void k_cnt(const int* __restrict__ rows, int* __restrict__ cnti, int E) {
    int i = blockIdx.x * 256 + threadIdx.x;
    if (i < E) atomicAdd(&cnti[rows[i]], 1);
}

// single-block exclusive scan over N counts -> base
__global__ void k_scan(const int* __restrict__ cnti, int* __restrict__ base, int N) {
    __shared__ int part[256];
    int t = threadIdx.x;
    int chunk = (N + 255) / 256;
    int lo = t * chunk, hi = lo + chunk < N ? lo + chunk : N;
    int s = 0;
    for (int i = lo; i < hi; ++i) s += cnti[i];
    part[t] = s;
    __syncthreads();
    for (int off = 1; off < 256; off <<= 1) {
        int v = (t >= off) ? part[t - off] : 0;
        __syncthreads();
        part[t] += v;
        __syncthreads();
    }
    int run = (t == 0) ? 0 : part[t - 1];
    for (int i = lo; i < hi; ++i) { base[i] = run; run += cnti[i]; }
}

__global__ void k_scatter(const int* __restrict__ rows, const int* __restrict__ cols,
                          const float* __restrict__ eattr,
                          const int* __restrict__ base, int* __restrict__ fill,
                          int* __restrict__ srow, int* __restrict__ scol,
                          float* __restrict__ sea, int E) {
    int e = blockIdx.x * 256 + threadIdx.x;
    if (e >= E) return;
    int r = rows[e];
    int pos = base[r] + atomicAdd(&fill[r], 1);
    srow[pos] = r;
    scol[pos] = cols[e];
    sea[pos * 2 + 0] = eattr[(size_t)e * 2 + 0];
    sea[pos * 2 + 1] = eattr[(size_t)e * 2 + 1];
}

__global__ void k_embed(const float* __restrict__ hin, const float* __restrict__ w,
                        const float* __restrict__ b, float* __restrict__ hout, int N) {
    int idx = blockIdx.x * 256 + threadIdx.x;
    if (idx >= N * HID) return;
    int n = idx >> 7, j = idx & 127;
    float s = b[j];
    const float* hr = &hin[n * 6];
#pragma unroll
    for (int k = 0; k < 6; ++k) s += hr[k] * w[k * HID + j];
    hout[idx] = s;
}

// pack weights for MFMA (hi/lo split): s-block = [hi 1024 | lo 1024], entry n*8 + (k&7)
__global__ void k_pack_w(const float* __restrict__ ew2, const float* __restrict__ cw1,
                         unsigned short* __restrict__ w2p, unsigned short* __restrict__ c1p) {
    int idx = blockIdx.x * 256 + threadIdx.x;
    if (idx >= 4 * 32768) return;
    int l = idx >> 15, r = idx & 32767;
    const float* src;
    unsigned short* dst;
    int k, n;
    if (r < 16384) {
        k = r >> 7; n = r & 127;
        src = ew2 + (size_t)l * 16384 + k * 128 + n;
        dst = w2p + (size_t)l * 32768;
    } else {
        int rr = r - 16384; k = rr >> 7; n = rr & 127;
        src = cw1 + (size_t)l * 16384 + k * 128 + n;
        dst = c1p + (size_t)l * 32768;
    }
    float f = *src;
    unsigned short hi = bf16hi(f);
    float rem = f - bf16tof(hi);
    int s = k >> 3;
    int b = s * 2048 + n * 8 + (k & 7);
    dst[b] = hi;
    dst[b + 1024] = bf16hi(rem);
}

// per-node GEMM1 hoist: Hrow = h @ W[0:128] + eb1, Hcol = h @ W[128:256]  (fp32, exact)
// (used once after embedding; subsequent layers fuse this into k_node)
__global__ __launch_bounds__(256, 2) void k_hpre(
    const float* __restrict__ h, const float* __restrict__ w,
    const float* __restrict__ eb1,
    float* __restrict__ Hrow, float* __restrict__ Hcol, int N)
{
    __shared__ __align__(16) float BH[64][132];
    const int t = threadIdx.x;
    const int tx = t & 15, ty = t >> 4;
    const int n0 = blockIdx.x * 64;

    for (int idx = t; idx < 64 * 32; idx += 256) {
        int r = idx >> 5, c4 = idx & 31;
        int n = n0 + r;
        float4 v0 = make_float4(0.f, 0.f, 0.f, 0.f);
        if (n < N) v0 = *(const float4*)&h[(size_t)n * HID + c4 * 4];
        *(float4*)&BH[r][c4 * 4] = v0;
    }
    __syncthreads();

    float ar[4][8], ac[4][8];
#pragma unroll
    for (int i = 0; i < 4; ++i)
#pragma unroll
        for (int j = 0; j < 8; ++j) { ar[i][j] = 0.f; ac[i][j] = 0.f; }

    const float* wr = &w[tx * 8];
    const float* wc = &w[128 * HID + tx * 8];
#pragma unroll 4
    for (int k = 0; k < HID; ++k) {
        float4 r0 = *(const float4*)&wr[k * HID];
        float4 r1 = *(const float4*)&wr[k * HID + 4];
        float4 c0 = *(const float4*)&wc[k * HID];
        float4 c1 = *(const float4*)&wc[k * HID + 4];
        float rv[8] = {r0.x, r0.y, r0.z, r0.w, r1.x, r1.y, r1.z, r1.w};
        float cv[8] = {c0.x, c0.y, c0.z, c0.w, c1.x, c1.y, c1.z, c1.w};
        float av[4];
#pragma unroll
        for (int i = 0; i < 4; ++i) av[i] = BH[ty * 4 + i][k];
#pragma unroll
        for (int i = 0; i < 4; ++i)
#pragma unroll
            for (int j = 0; j < 8; ++j) {
                ar[i][j] += av[i] * rv[j];
                ac[i][j] += av[i] * cv[j];
            }
    }
#pragma unroll
    for (int i = 0; i < 4; ++i) {
        int n = n0 + ty * 4 + i;
        if (n < N) {
#pragma unroll
            for (int j = 0; j < 8; ++j) {
                Hrow[(size_t)n * HID + tx * 8 + j] = ar[i][j] + eb1[tx * 8 + j];
                Hcol[(size_t)n * HID + tx * 8 + j] = ac[i][j];
            }
        }
    }
}

// MFMA edge kernel over SORTED edges: 32 edges/block, 4 waves = 2 groups x 2
// channel-half waves. Each wave computes 64 of the 128 output channels for its
// group's 16 edges -> accumulators/fragments halve (16 regs each), no spill.
// Shared [16][128] split-bf16 tile per group carries e_act then m; gate
// partials exchanged via LDS; 3 barriers. All fragment arrays use STATIC
// unrolled indices only. launch_bounds(256,7): 73-VGPR cap (needs ~36-40,
// spill-free), 7 blocks/CU = 87.5% occupancy, LDS 7x18.9=132.6 KB.
__global__ __launch_bounds__(256, 7) void k_edge_mfma(
    const float* __restrict__ Hrow, const float* __restrict__ Hcol,
    const float* __restrict__ x,
    const int* __restrict__ srow, const int* __restrict__ scol,
    const float* __restrict__ sea,
    const float* __restrict__ ew1_tail,
    const unsigned short* __restrict__ w2p, const float* __restrict__ eb2,
    const float* __restrict__ aw, const float* __restrict__ ab,
    const unsigned short* __restrict__ c1p, const float* __restrict__ cb1,
    const float* __restrict__ cw2,
    float* __restrict__ aggh, float* __restrict__ aggx, int E)
{
    __shared__ __align__(16) unsigned short tHi[2][16][136];
    __shared__ __align__(16) unsigned short tLo[2][16][136];
    __shared__ float sGate[2][2][16];
    __shared__ float sCD[32][4];
    __shared__ float sEA[32][2];
    __shared__ int sRow[32], sCol[32];

    const int t = threadIdx.x;
    const int wv = t >> 6, lane = t & 63;
    const int grp = wv >> 1, hf = wv & 1;
    const int quad = lane >> 4, ln = lane & 15;
    const int e0 = blockIdx.x * 32;

    // metadata: each wave writes its group's 16 edges (both waves write identical
    // values to the same addresses -> race-free by value; wave-internal ordering
    // makes them visible to this wave's own reads without a barrier)
    if (lane < 16) {
        int eg = e0 + grp * 16 + lane;
        int ec = eg < E ? eg : E - 1;
        int r = srow[ec], c = scol[ec];
        sRow[grp * 16 + lane] = r; sCol[grp * 16 + lane] = c;
        float dx = x[r * 3 + 0] - x[c * 3 + 0];
        float dy = x[r * 3 + 1] - x[c * 3 + 1];
        float dz = x[r * 3 + 2] - x[c * 3 + 2];
        sCD[grp * 16 + lane][0] = dx;
        sCD[grp * 16 + lane][1] = dy;
        sCD[grp * 16 + lane][2] = dz;
        sCD[grp * 16 + lane][3] = dx * dx + dy * dy + dz * dz;
        sEA[grp * 16 + lane][0] = sea[(size_t)ec * 2 + 0];
        sEA[grp * 16 + lane][1] = sea[(size_t)ec * 2 + 1];
    }

    const int eM = grp * 16 + ln;
    const int rn = sRow[eM], cn = sCol[eM];
    const float rad = sCD[eM][3], ea0 = sEA[eM][0], ea1 = sEA[eM][1];

    // ---- phase 1: e_act (fused GEMM1) for this wave's channel half; edge = ln
#pragma unroll
    for (int kk = 0; kk < 2; ++kk) {
        const int kc = hf * 2 + kk;
        const int fb = kc * 32 + quad * 8;
        f32x4 a0 = *(const f32x4*)(Hrow + (size_t)rn * HID + fb);
        f32x4 a1 = *(const f32x4*)(Hrow + (size_t)rn * HID + fb + 4);
        f32x4 c0 = *(const f32x4*)(Hcol + (size_t)cn * HID + fb);
        f32x4 c1 = *(const f32x4*)(Hcol + (size_t)cn * HID + fb + 4);
        f32x4 w60 = *(const f32x4*)(ew1_tail + fb);
        f32x4 w61 = *(const f32x4*)(ew1_tail + fb + 4);
        f32x4 w70 = *(const f32x4*)(ew1_tail + 128 + fb);
        f32x4 w71 = *(const f32x4*)(ew1_tail + 128 + fb + 4);
        f32x4 w80 = *(const f32x4*)(ew1_tail + 256 + fb);
        f32x4 w81 = *(const f32x4*)(ew1_tail + 256 + fb + 4);
        bf16x8 ahi, alo;
#pragma unroll
        for (int j = 0; j < 4; ++j) {
            float s0 = a0[j] + c0[j] + rad * w60[j] + ea0 * w70[j] + ea1 * w80[j];
            float s1 = a1[j] + c1[j] + rad * w61[j] + ea0 * w71[j] + ea1 * w81[j];
            s0 = silu_f(s0);
            s1 = silu_f(s1);
            unsigned short h0 = bf16hi(s0), h1 = bf16hi(s1);
            ahi[j] = (short)h0;
            ahi[j + 4] = (short)h1;
            alo[j] = (short)bf16hi(s0 - bf16tof(h0));
            alo[j + 4] = (short)bf16hi(s1 - bf16tof(h1));
        }
        *(bf16x8*)&tHi[grp][ln][fb] = ahi;
        *(bf16x8*)&tLo[grp][ln][fb] = alo;
    }
    __syncthreads();   // barrier A: e_act tile complete

    // ---- read full-K GEMM2 A-fragments (static indices)
    bf16x8 g1hi[4], g1lo[4];
#pragma unroll
    for (int kc = 0; kc < 4; ++kc) {
        g1hi[kc] = *(const bf16x8*)&tHi[grp][ln][kc * 32 + quad * 8];
        g1lo[kc] = *(const bf16x8*)&tLo[grp][ln][kc * 32 + quad * 8];
    }

    // ---- GEMM2: this wave's 4 output tiles (channels hf*64 .. hf*64+63)
    f32x4 acc2[4];
#pragma unroll
    for (int i = 0; i < 4; ++i) acc2[i] = (f32x4){0.f, 0.f, 0.f, 0.f};
#pragma unroll
    for (int t8l = 0; t8l < 4; ++t8l) {
        const int t8 = hf * 4 + t8l;
        const unsigned short* bg = w2p + quad * 2048 + ln * 8 + t8 * 128;
#pragma unroll
        for (int kc = 0; kc < 4; ++kc) {
            bf16x8 bhi = *(const bf16x8*)(bg + kc * 8192);
            bf16x8 blo = *(const bf16x8*)(bg + kc * 8192 + 1024);
            acc2[t8l] = __builtin_amdgcn_mfma_f32_16x16x32_bf16(g1hi[kc], bhi, acc2[t8l], 0, 0, 0);
            acc2[t8l] = __builtin_amdgcn_mfma_f32_16x16x32_bf16(g1lo[kc], bhi, acc2[t8l], 0, 0, 0);
            acc2[t8l] = __builtin_amdgcn_mfma_f32_16x16x32_bf16(g1hi[kc], blo, acc2[t8l], 0, 0, 0);
        }
    }

    // ---- silu + gate partial over this half's channels
    float pr[4] = {0.f, 0.f, 0.f, 0.f};
#pragma unroll
    for (int t8l = 0; t8l < 4; ++t8l) {
        int n = (hf * 4 + t8l) * 16 + ln;
        float bb = eb2[n], awn = aw[n];
#pragma unroll
        for (int r = 0; r < 4; ++r) {
            float v = silu_f(acc2[t8l][r] + bb);
            acc2[t8l][r] = v;
            pr[r] += v * awn;
        }
    }
#pragma unroll
    for (int r = 0; r < 4; ++r) {
        float p = pr[r];
        p += __shfl_xor(p, 1);
        p += __shfl_xor(p, 2);
        p += __shfl_xor(p, 4);
        p += __shfl_xor(p, 8);
        pr[r] = p;   // partial gate dot for edge quad*4+r
    }
    if (ln == 0) {
#pragma unroll
        for (int r = 0; r < 4; ++r) sGate[grp][hf][quad * 4 + r] = pr[r];
    }
    __syncthreads();   // barrier B: gate partials ready; all e_act reads done

    float gate[4];
    {
        float ab0 = ab[0];
#pragma unroll
        for (int r = 0; r < 4; ++r)
            gate[r] = sigmoid_f(sGate[grp][0][quad * 4 + r] +
                                sGate[grp][1][quad * 4 + r] + ab0);
    }

    // ---- gate + write m (this half) into the tile (overwrites own e_act half)
#pragma unroll
    for (int t8l = 0; t8l < 4; ++t8l) {
        int n = (hf * 4 + t8l) * 16 + ln;
#pragma unroll
        for (int r = 0; r < 4; ++r) {
            float v = acc2[t8l][r] * gate[r];
            acc2[t8l][r] = v;                 // keep gated m (fp32) for agg_h
            unsigned short hi = bf16hi(v);
            float rem = v - bf16tof(hi);
            tHi[grp][quad * 4 + r][n] = hi;
            tLo[grp][quad * 4 + r][n] = bf16hi(rem);
        }
    }

    // ---- agg_h: run-segmented reduction (this half's channels, exact fp32)
    {
        int i = 0;
        while (i < 16) {
            int node = sRow[grp * 16 + i];
            int j = i + 1;
            while (j < 16 && sRow[grp * 16 + j] == node) ++j;
#pragma unroll
            for (int t8l = 0; t8l < 4; ++t8l) {
                float s = 0.f;
#pragma unroll
                for (int r = 0; r < 4; ++r) {
                    int el = quad * 4 + r;
                    bool ok = (el >= i) && (el < j) && (e0 + grp * 16 + el < E);
                    s += ok ? acc2[t8l][r] : 0.f;
                }
                s += __shfl_xor(s, 16);
                s += __shfl_xor(s, 32);
                if (quad == (t8l & 3))
                    atomicAdd(&aggh[(size_t)node * HID + (hf * 4 + t8l) * 16 + ln], s);
            }
            i = j;
        }
    }
    __syncthreads();   // barrier C: m tile complete

    // ---- GEMM3 (this wave's half of output channels; full-K m fragments)
    bf16x8 g3hi[4], g3lo[4];
#pragma unroll
    for (int kc = 0; kc < 4; ++kc) {
        g3hi[kc] = *(const bf16x8*)&tHi[grp][ln][kc * 32 + quad * 8];
        g3lo[kc] = *(const bf16x8*)&tLo[grp][ln][kc * 32 + quad * 8];
    }
    f32x4 acc3[4];
#pragma unroll
    for (int i = 0; i < 4; ++i) acc3[i] = (f32x4){0.f, 0.f, 0.f, 0.f};
#pragma unroll
    for (int t8l = 0; t8l < 4; ++t8l) {
        const int t8 = hf * 4 + t8l;
        const unsigned short* bg = c1p + quad * 2048 + ln * 8 + t8 * 128;
#pragma unroll
        for (int kc = 0; kc < 4; ++kc) {
            bf16x8 bhi = *(const bf16x8*)(bg + kc * 8192);
            bf16x8 blo = *(const bf16x8*)(bg + kc * 8192 + 1024);
            acc3[t8l] = __builtin_amdgcn_mfma_f32_16x16x32_bf16(g3hi[kc], bhi, acc3[t8l], 0, 0, 0);
            acc3[t8l] = __builtin_amdgcn_mfma_f32_16x16x32_bf16(g3lo[kc], bhi, acc3[t8l], 0, 0, 0);
            acc3[t8l] = __builtin_amdgcn_mfma_f32_16x16x32_bf16(g3hi[kc], blo, acc3[t8l], 0, 0, 0);
        }
    }
    {
        float pr3[4] = {0.f, 0.f, 0.f, 0.f};
#pragma unroll
        for (int t8l = 0; t8l < 4; ++t8l) {
            int n = (hf * 4 + t8l) * 16 + ln;
            float bb = cb1[n], cwn = cw2[n];
#pragma unroll
            for (int r = 0; r < 4; ++r) {
                float u = silu_f(acc3[t8l][r] + bb);
                pr3[r] += u * cwn;
            }
        }
#pragma unroll
        for (int r = 0; r < 4; ++r) {
            float p = pr3[r];
            p += __shfl_xor(p, 1);
            p += __shfl_xor(p, 2);
            p += __shfl_xor(p, 4);
            p += __shfl_xor(p, 8);
            pr3[r] = p;   // partial w (this half); halves sum via atomics
        }
        // ---- agg_x: run-segmented reduction (partial w; both waves atomicAdd)
        int i = 0;
        while (i < 16) {
            int node = sRow[grp * 16 + i];
            int j = i + 1;
            while (j < 16 && sRow[grp * 16 + j] == node) ++j;
            float s = 0.f;
            if (ln < 3) {
#pragma unroll
                for (int r = 0; r < 4; ++r) {
                    int el = quad * 4 + r;
                    int m = grp * 16 + el;
                    bool ok = (el >= i) && (el < j) && (e0 + m < E);
                    s += ok ? sCD[m][ln] * pr3[r] : 0.f;
                }
            }
            s += __shfl_xor(s, 16);
            s += __shfl_xor(s, 32);
            if (quad == 0 && ln < 3)
                atomicAdd(&aggx[node * 3 + ln], s);
            i = j;
        }
    }
}

// 32 nodes per block, 256 threads (fp32); zeroes aggh/aggx after reading
// (replaces per-layer memsets). Optionally fuses next layer's Hrow/Hcol
// precompute (hpre, with eb1 folded into Hrow) on the fresh h tile.
__global__ __launch_bounds__(256, 3) void k_node(
    float* __restrict__ h, float* __restrict__ aggh,
    float* __restrict__ aggx, const int* __restrict__ cnti,
    float* __restrict__ x, float* __restrict__ vel,
    const float* __restrict__ vw1, const float* __restrict__ vb1,
    const float* __restrict__ vw2, const float* __restrict__ vb2,
    const float* __restrict__ nw1, const float* __restrict__ nb1,
    const float* __restrict__ nw2, const float* __restrict__ nb2,
    int N,
    const float* __restrict__ ew1n, const float* __restrict__ eb1n,
    float* __restrict__ Hrow, float* __restrict__ Hcol)
{
    __shared__ __align__(16) float BH[32][132];
    __shared__ __align__(16) float BG[32][132];
    const int t = threadIdx.x;
    const int tx = t & 15, ty = t >> 4;
    const int n0 = blockIdx.x * 32;

    for (int idx = t; idx < 32 * 32; idx += 256) {
        int r = idx >> 5, c4 = idx & 31;
        int n = n0 + r;
        float4 v0 = make_float4(0.f, 0.f, 0.f, 0.f), v1 = v0;
        if (n < N) {
            v0 = *(const float4*)&h[(size_t)n * HID + c4 * 4];
            v1 = *(const float4*)&aggh[(size_t)n * HID + c4 * 4];
            *(float4*)&aggh[(size_t)n * HID + c4 * 4] =
                make_float4(0.f, 0.f, 0.f, 0.f);   // zero for next layer
        }
        *(float4*)&BH[r][c4 * 4] = v0;
        *(float4*)&BG[r][c4 * 4] = v1;
    }
    __syncthreads();

    {
        float acc[2][8];
#pragma unroll
        for (int i = 0; i < 2; ++i)
#pragma unroll
            for (int j = 0; j < 8; ++j) acc[i][j] = 0.f;
        const float* wp = &vw1[tx * 8];
#pragma unroll 4
        for (int k = 0; k < HID; ++k) {
            float4 w0 = *(const float4*)&wp[k * HID];
            float4 w1v = *(const float4*)&wp[k * HID + 4];
            float wv[8] = {w0.x, w0.y, w0.z, w0.w, w1v.x, w1v.y, w1v.z, w1v.w};
            float av[2];
#pragma unroll
            for (int i = 0; i < 2; ++i) av[i] = BH[ty * 2 + i][k];
#pragma unroll
            for (int i = 0; i < 2; ++i)
#pragma unroll
                for (int j = 0; j < 8; ++j) acc[i][j] += av[i] * wv[j];
        }
        float bb[8], w2v[8];
#pragma unroll
        for (int j = 0; j < 8; ++j) { bb[j] = vb1[tx * 8 + j]; w2v[j] = vw2[tx * 8 + j]; }
        float vb20 = vb2[0];
#pragma unroll
        for (int i = 0; i < 2; ++i) {
            float p = 0.f;
#pragma unroll
            for (int j = 0; j < 8; ++j) p += silu_f(acc[i][j] + bb[j]) * w2v[j];
            p += __shfl_xor(p, 1);
            p += __shfl_xor(p, 2);
            p += __shfl_xor(p, 4);
            p += __shfl_xor(p, 8);
            float vs = p + vb20;
            if (tx == 0) {
                int n = n0 + ty * 2 + i;
                if (n < N) {
                    float cc = fmaxf((float)cnti[n], 1.0f);
#pragma unroll
                    for (int d = 0; d < 3; ++d) {
                        float vn = vs * vel[n * 3 + d];
                        float xn = x[n * 3 + d] + aggx[n * 3 + d] / cc + vn;
                        vel[n * 3 + d] = vn;
                        x[n * 3 + d] = xn;
                        aggx[n * 3 + d] = 0.f;   // zero for next layer
                    }
                }
            }
        }
    }

    float acc2[2][8];
#pragma unroll
    for (int i = 0; i < 2; ++i)
#pragma unroll
        for (int j = 0; j < 8; ++j) acc2[i][j] = 0.f;
    {
        const float* wp = &nw1[tx * 8];
#pragma unroll 4
        for (int k = 0; k < HID; ++k) {
            float4 w0 = *(const float4*)&wp[k * HID];
            float4 w1v = *(const float4*)&wp[k * HID + 4];
            float wv[8] = {w0.x, w0.y, w0.z, w0.w, w1v.x, w1v.y, w1v.z, w1v.w};
            float av[2];
#pragma unroll
            for (int i = 0; i < 2; ++i) av[i] = BH[ty * 2 + i][k];
#pragma unroll
            for (int i = 0; i < 2; ++i)
#pragma unroll
                for (int j = 0; j < 8; ++j) acc2[i][j] += av[i] * wv[j];
        }
        const float* wp2 = &nw1[128 * HID + tx * 8];
#pragma unroll 4
        for (int k = 0; k < HID; ++k) {
            float4 w0 = *(const float4*)&wp2[k * HID];
            float4 w1v = *(const float4*)&wp2[k * HID + 4];
            float wv[8] = {w0.x, w0.y, w0.z, w0.w, w1v.x, w1v.y, w1v.z, w1v.w};
            float av[2];
#pragma unroll
            for (int i = 0; i < 2; ++i) av[i] = BG[ty * 2 + i][k];
#pragma unroll
            for (int i = 0; i < 2; ++i)
#pragma unroll
                for (int j = 0; j < 8; ++j) acc2[i][j] += av[i] * wv[j];
        }
    }
    __syncthreads();
    {
        float bb[8];
#pragma unroll
        for (int j = 0; j < 8; ++j) bb[j] = nb1[tx * 8 + j];
#pragma unroll
        for (int i = 0; i < 2; ++i)
#pragma unroll
            for (int j = 0; j < 8; ++j)
                BH[ty * 2 + i][tx * 8 + j] = silu_f(acc2[i][j] + bb[j]);
    }
    __syncthreads();
    float acc3[2][8];
#pragma unroll
    for (int i = 0; i < 2; ++i)
#pragma unroll
        for (int j = 0; j < 8; ++j) acc3[i][j] = 0.f;
    {
        const float* wp = &nw2[tx * 8];
#pragma unroll 4
        for (int k = 0; k < HID; ++k) {
            float4 w0 = *(const float4*)&wp[k * HID];
            float4 w1v = *(const float4*)&wp[k * HID + 4];
            float wv[8] = {w0.x, w0.y, w0.z, w0.w, w1v.x, w1v.y, w1v.z, w1v.w};
            float av[2];
#pragma unroll
            for (int i = 0; i < 2; ++i) av[i] = BH[ty * 2 + i][k];
#pragma unroll
            for (int i = 0; i < 2; ++i)
#pragma unroll
                for (int j = 0; j < 8; ++j) acc3[i][j] += av[i] * wv[j];
        }
    }
    float hv[2][8];
    {
        float bb[8];
#pragma unroll
        for (int j = 0; j < 8; ++j) bb[j] = nb2[tx * 8 + j];
#pragma unroll
        for (int i = 0; i < 2; ++i) {
#pragma unroll
            for (int j = 0; j < 8; ++j) hv[i][j] = acc3[i][j] + bb[j];
            int n = n0 + ty * 2 + i;
            if (n < N) {
#pragma unroll
                for (int j = 0; j < 8; ++j)
                    h[(size_t)n * HID + tx * 8 + j] = hv[i][j];
            }
        }
    }

    if (ew1n == nullptr) return;

    // ---- fused hpre for next layer: Hrow/Hcol = h_new @ ew1n[0:128 / 128:256]
    __syncthreads();   // all reads of BH (acc3 GEMM) complete
#pragma unroll
    for (int i = 0; i < 2; ++i)
#pragma unroll
        for (int j = 0; j < 8; ++j)
            BH[ty * 2 + i][tx * 8 + j] = hv[i][j];
    __syncthreads();

    float ar[2][8], ac[2][8];
#pragma unroll
    for (int i = 0; i < 2; ++i)
#pragma unroll
        for (int j = 0; j < 8; ++j) { ar[i][j] = 0.f; ac[i][j] = 0.f; }
    const float* wr = &ew1n[tx * 8];
    const float* wc = &ew1n[128 * HID + tx * 8];
#pragma unroll 4
    for (int k = 0; k < HID; ++k) {
        float4 r0 = *(const float4*)&wr[k * HID];
        float4 r1 = *(const float4*)&wr[k * HID + 4];
        float4 c0 = *(const float4*)&wc[k * HID];
        float4 c1 = *(const float4*)&wc[k * HID + 4];
        float rv[8] = {r0.x, r0.y, r0.z, r0.w, r1.x, r1.y, r1.z, r1.w};
        float cv[8] = {c0.x, c0.y, c0.z, c0.w, c1.x, c1.y, c1.z, c1.w};
        float av[2];
#pragma unroll
        for (int i = 0; i < 2; ++i) av[i] = BH[ty * 2 + i][k];
#pragma unroll
        for (int i = 0; i < 2; ++i)
#pragma unroll
            for (int j = 0; j < 8; ++j) {
                ar[i][j] += av[i] * rv[j];
                ac[i][j] += av[i] * cv[j];
            }
    }
#pragma unroll
    for (int i = 0; i < 2; ++i) {
        int n = n0 + ty * 2 + i;
        if (n < N) {
#pragma unroll
            for (int j = 0; j < 8; ++j) {
                Hrow[(size_t)n * HID + tx * 8 + j] = ar[i][j] + eb1n[tx * 8 + j];
                Hcol[(size_t)n * HID + tx * 8 + j] = ac[i][j];
            }
        }
    }
}

__global__ void k_proj(const float* __restrict__ h, const float* __restrict__ pw,
                       const float* __restrict__ pb, float* __restrict__ out, int N) {
    int idx = blockIdx.x * 256 + threadIdx.x;
    if (idx >= N * 3) return;
    int n = idx / 3, p = idx % 3;
    float s = pb[p];
    const float* hr = &h[(size_t)n * HID];
#pragma unroll 8
    for (int k = 0; k < HID; ++k) s += hr[k] * pw[k * 3 + p];
    out[idx] = s;
}

extern "C" void kernel_launch(void* const* d_in, const int* in_sizes, int n_in,
                              void* d_out, int out_size, void* d_ws, size_t ws_size,
                              hipStream_t stream)
{
    const float* h_in  = (const float*)d_in[0];
    const float* x_in  = (const float*)d_in[1];
    const float* v_in  = (const float*)d_in[2];
    const float* eattr = (const float*)d_in[3];
    const int*   edges = (const int*)d_in[4];
    const float* emb_w = (const float*)d_in[5];
    const float* emb_b = (const float*)d_in[6];
    const float* ew1   = (const float*)d_in[7];
    const float* eb1   = (const float*)d_in[8];
    const float* ew2   = (const float*)d_in[9];
    const float* eb2   = (const float*)d_in[10];
    const float* aw    = (const float*)d_in[11];
    const float* ab    = (const float*)d_in[12];
    const float* nw1   = (const float*)d_in[13];
    const float* nb1   = (const float*)d_in[14];
    const float* nw2   = (const float*)d_in[15];
    const float* nb2   = (const float*)d_in[16];
    const float* cw1   = (const float*)d_in[17];
    const float* cb1   = (const float*)d_in[18];
    const float* cw2   = (const float*)d_in[19];
    const float* vw1   = (const float*)d_in[20];
    const float* vb1   = (const float*)d_in[21];
    const float* vw2   = (const float*)d_in[22];
    const float* vb2   = (const float*)d_in[23];
    const float* pw    = (const float*)d_in[24];
    const float* pb    = (const float*)d_in[25];

    const int N = in_sizes[0] / 6;
    const int E = in_sizes[4] / 2;
    const int* rows = edges;
    const int* cols = edges + E;

    float* ws   = (float*)d_ws;
    float* hbuf = ws;  ws += (size_t)N * HID;
    float* aggh = ws;  ws += (size_t)N * HID;
    float* aggx = ws;  ws += (size_t)N * 3;
    float* xb   = ws;  ws += (size_t)N * 3;
    float* vb   = ws;  ws += (size_t)N * 3;
    float* sea  = ws;  ws += (size_t)E * 2;
    float* Hrow = ws;  ws += (size_t)N * HID;
    float* Hcol = ws;  ws += (size_t)N * HID;
    int* wi = (int*)ws;
    int* cnti = wi;  wi += N;
    int* basei = wi; wi += N;
    int* fill = wi;  wi += N;
    int* srow = wi;  wi += E;
    int* scol = wi;  wi += E;
    unsigned short* us = (unsigned short*)wi;
    unsigned short* w2p = us;  us += 4 * 32768;
    unsigned short* c1p = us;  us += 4 * 32768;
    float* outp = (float*)d_out;

    hipMemcpyAsync(xb, x_in, (size_t)N * 3 * sizeof(float), hipMemcpyDeviceToDevice, stream);
    hipMemcpyAsync(vb, v_in, (size_t)N * 3 * sizeof(float), hipMemcpyDeviceToDevice, stream);
    hipMemsetAsync(cnti, 0, 2 * N * sizeof(int), stream);  // cnti+basei; fill separate
    hipMemsetAsync(fill, 0, N * sizeof(int), stream);
    hipMemsetAsync(aggh, 0, (size_t)N * HID * sizeof(float), stream);  // layer 0 only;
    hipMemsetAsync(aggx, 0, (size_t)N * 3 * sizeof(float), stream);    // k_node re-zeroes
    k_cnt<<<(E + 255) / 256, 256, 0, stream>>>(rows, cnti, E);
    k_scan<<<1, 256, 0, stream>>>(cnti, basei, N);
    k_scatter<<<(E + 255) / 256, 256, 0, stream>>>(rows, cols, eattr, basei, fill,
                                                   srow, scol, sea, E);
    k_pack_w<<<(4 * 32768 + 255) / 256, 256, 0, stream>>>(ew2, cw1, w2p, c1p);
    k_embed<<<(N * HID + 255) / 256, 256, 0, stream>>>(h_in, emb_w, emb_b, hbuf, N);
    k_hpre<<<(N + 63) / 64, 256, 0, stream>>>(hbuf, ew1, eb1, Hrow, Hcol, N);

    for (int l = 0; l < 4; ++l) {
        k_edge_mfma<<<(E + 31) / 32, 256, 0, stream>>>(
            Hrow, Hcol, xb, srow, scol, sea,
            ew1 + (size_t)l * 33152 + 256 * HID,
            w2p + (size_t)l * 32768, eb2 + l * HID,
            aw + l * HID, ab + l,
            c1p + (size_t)l * 32768, cb1 + l * HID, cw2 + l * HID,
            aggh, aggx, E);
        k_node<<<(N + 31) / 32, 256, 0, stream>>>(
            hbuf, aggh, aggx, cnti, xb, vb,
            vw1 + (size_t)l * HID * HID, vb1 + l * HID, vw2 + l * HID, vb2 + l,
            nw1 + (size_t)l * 2 * HID * HID, nb1 + l * HID,
            nw2 + (size_t)l * HID * HID, nb2 + l * HID, N,
            (l < 3) ? (ew1 + (size_t)(l + 1) * 33152) : nullptr,
            (l < 3) ? (eb1 + (size_t)(l + 1) * HID) : nullptr, Hrow, Hcol);
    }
    k_proj<<<(N * 3 + 255) / 256, 256, 0, stream>>>(hbuf, pw, pb, outp, N);
    hipMemcpyAsync(outp + (size_t)N * 3, xb, (size_t)N * 3 * sizeof(float), hipMemcpyDeviceToDevice, stream);
    hipMemcpyAsync(outp + (size_t)N * 6, vb, (size_t)N * 3 * sizeof(float), hipMemcpyDeviceToDevice, stream);
}

// Round 12
// 895.811 us; speedup vs baseline: 1.4406x; 1.2970x over previous
//
#include <hip/hip_runtime.h>
#include <math.h>

#define HID 128

typedef __attribute__((ext_vector_type(8))) short bf16x8;
typedef __attribute__((ext_vector_type(4))) float f32x4;

__device__ __forceinline__ float silu_f(float v) {
    return v * __builtin_amdgcn_rcpf(1.0f + __expf(-v));
}
__device__ __forceinline__ float sigmoid_f(float v) {
    return __builtin_amdgcn_rcpf(1.0f + __expf(-v));
}
__device__ __forceinline__ unsigned short bf16hi(float f) {
    return (unsigned short)(__float_as_uint(f) >> 16);
}
__device__ __forceinline__ float bf16tof(unsigned short u) {
    return __uint_as_float(((unsigned int)u) << 16);
}

// ---------- CSR / sort-by-row (rows static across layers; built once per call) ----------
__global__ void k_cnt(const int* __restrict__ rows, int* __restrict__ cnti, int E) {
    int i = blockIdx.x * 256 + threadIdx.x;
    if (i < E) atomicAdd(&cnti[rows[i]], 1);
}

// single-block exclusive scan over N counts -> base
__global__ void k_scan(const int* __restrict__ cnti, int* __restrict__ base, int N) {
    __shared__ int part[256];
    int t = threadIdx.x;
    int chunk = (N + 255) / 256;
    int lo = t * chunk, hi = lo + chunk < N ? lo + chunk : N;
    int s = 0;
    for (int i = lo; i < hi; ++i) s += cnti[i];
    part[t] = s;
    __syncthreads();
    for (int off = 1; off < 256; off <<= 1) {
        int v = (t >= off) ? part[t - off] : 0;
        __syncthreads();
        part[t] += v;
        __syncthreads();
    }
    int run = (t == 0) ? 0 : part[t - 1];
    for (int i = lo; i < hi; ++i) { base[i] = run; run += cnti[i]; }
}

__global__ void k_scatter(const int* __restrict__ rows, const int* __restrict__ cols,
                          const float* __restrict__ eattr,
                          const int* __restrict__ base, int* __restrict__ fill,
                          int* __restrict__ srow, int* __restrict__ scol,
                          float* __restrict__ sea, int E) {
    int e = blockIdx.x * 256 + threadIdx.x;
    if (e >= E) return;
    int r = rows[e];
    int pos = base[r] + atomicAdd(&fill[r], 1);
    srow[pos] = r;
    scol[pos] = cols[e];
    sea[pos * 2 + 0] = eattr[(size_t)e * 2 + 0];
    sea[pos * 2 + 1] = eattr[(size_t)e * 2 + 1];
}

__global__ void k_embed(const float* __restrict__ hin, const float* __restrict__ w,
                        const float* __restrict__ b, float* __restrict__ hout, int N) {
    int idx = blockIdx.x * 256 + threadIdx.x;
    if (idx >= N * HID) return;
    int n = idx >> 7, j = idx & 127;
    float s = b[j];
    const float* hr = &hin[n * 6];
#pragma unroll
    for (int k = 0; k < 6; ++k) s += hr[k] * w[k * HID + j];
    hout[idx] = s;
}

// pack weights for MFMA (hi/lo split): s-block = [hi 1024 | lo 1024], entry n*8 + (k&7)
__global__ void k_pack_w(const float* __restrict__ ew2, const float* __restrict__ cw1,
                         unsigned short* __restrict__ w2p, unsigned short* __restrict__ c1p) {
    int idx = blockIdx.x * 256 + threadIdx.x;
    if (idx >= 4 * 32768) return;
    int l = idx >> 15, r = idx & 32767;
    const float* src;
    unsigned short* dst;
    int k, n;
    if (r < 16384) {
        k = r >> 7; n = r & 127;
        src = ew2 + (size_t)l * 16384 + k * 128 + n;
        dst = w2p + (size_t)l * 32768;
    } else {
        int rr = r - 16384; k = rr >> 7; n = rr & 127;
        src = cw1 + (size_t)l * 16384 + k * 128 + n;
        dst = c1p + (size_t)l * 32768;
    }
    float f = *src;
    unsigned short hi = bf16hi(f);
    float rem = f - bf16tof(hi);
    int s = k >> 3;
    int b = s * 2048 + n * 8 + (k & 7);
    dst[b] = hi;
    dst[b + 1024] = bf16hi(rem);
}

// pack node-phase weights: vw1 / nw1(two halves) / nw2 / ew1 rows 0:128, 128:256
// all as standard 128x128 K-major packed (same format as w2p).
__global__ void k_pack_node(const float* __restrict__ vw1, const float* __restrict__ nw1,
                            const float* __restrict__ nw2, const float* __restrict__ ew1,
                            unsigned short* __restrict__ v1p, unsigned short* __restrict__ n1ap,
                            unsigned short* __restrict__ n1bp, unsigned short* __restrict__ n2p,
                            unsigned short* __restrict__ hrp, unsigned short* __restrict__ hcp) {
    int idx = blockIdx.x * 256 + threadIdx.x;
    if (idx >= 4 * 6 * 16384) return;
    int l = idx / (6 * 16384);
    int r = idx % (6 * 16384);
    int m = r / 16384;
    int e = r % 16384;
    int k = e >> 7, n = e & 127;
    const float* src;
    unsigned short* dst;
    switch (m) {
        case 0: src = vw1 + (size_t)l * 16384 + k * 128 + n;            dst = v1p  + (size_t)l * 32768; break;
        case 1: src = nw1 + (size_t)l * 32768 + k * 128 + n;            dst = n1ap + (size_t)l * 32768; break;
        case 2: src = nw1 + (size_t)l * 32768 + (128 + k) * 128 + n;    dst = n1bp + (size_t)l * 32768; break;
        case 3: src = nw2 + (size_t)l * 16384 + k * 128 + n;            dst = n2p  + (size_t)l * 32768; break;
        case 4: src = ew1 + (size_t)l * 33152 + k * 128 + n;            dst = hrp  + (size_t)l * 32768; break;
        default: src = ew1 + (size_t)l * 33152 + (128 + k) * 128 + n;   dst = hcp  + (size_t)l * 32768; break;
    }
    float f = *src;
    unsigned short hi = bf16hi(f);
    float rem = f - bf16tof(hi);
    int s = k >> 3;
    int b = s * 2048 + n * 8 + (k & 7);
    dst[b] = hi;
    dst[b + 1024] = bf16hi(rem);
}

// per-node GEMM1 hoist: Hrow = h @ W[0:128] + eb1, Hcol = h @ W[128:256]  (fp32, exact)
// (used once after embedding; subsequent layers fuse this into k_node_mfma)
__global__ __launch_bounds__(256, 2) void k_hpre(
    const float* __restrict__ h, const float* __restrict__ w,
    const float* __restrict__ eb1,
    float* __restrict__ Hrow, float* __restrict__ Hcol, int N)
{
    __shared__ __align__(16) float BH[64][132];
    const int t = threadIdx.x;
    const int tx = t & 15, ty = t >> 4;
    const int n0 = blockIdx.x * 64;

    for (int idx = t; idx < 64 * 32; idx += 256) {
        int r = idx >> 5, c4 = idx & 31;
        int n = n0 + r;
        float4 v0 = make_float4(0.f, 0.f, 0.f, 0.f);
        if (n < N) v0 = *(const float4*)&h[(size_t)n * HID + c4 * 4];
        *(float4*)&BH[r][c4 * 4] = v0;
    }
    __syncthreads();

    float ar[4][8], ac[4][8];
#pragma unroll
    for (int i = 0; i < 4; ++i)
#pragma unroll
        for (int j = 0; j < 8; ++j) { ar[i][j] = 0.f; ac[i][j] = 0.f; }

    const float* wr = &w[tx * 8];
    const float* wc = &w[128 * HID + tx * 8];
#pragma unroll 4
    for (int k = 0; k < HID; ++k) {
        float4 r0 = *(const float4*)&wr[k * HID];
        float4 r1 = *(const float4*)&wr[k * HID + 4];
        float4 c0 = *(const float4*)&wc[k * HID];
        float4 c1 = *(const float4*)&wc[k * HID + 4];
        float rv[8] = {r0.x, r0.y, r0.z, r0.w, r1.x, r1.y, r1.z, r1.w};
        float cv[8] = {c0.x, c0.y, c0.z, c0.w, c1.x, c1.y, c1.z, c1.w};
        float av[4];
#pragma unroll
        for (int i = 0; i < 4; ++i) av[i] = BH[ty * 4 + i][k];
#pragma unroll
        for (int i = 0; i < 4; ++i)
#pragma unroll
            for (int j = 0; j < 8; ++j) {
                ar[i][j] += av[i] * rv[j];
                ac[i][j] += av[i] * cv[j];
            }
    }
#pragma unroll
    for (int i = 0; i < 4; ++i) {
        int n = n0 + ty * 4 + i;
        if (n < N) {
#pragma unroll
            for (int j = 0; j < 8; ++j) {
                Hrow[(size_t)n * HID + tx * 8 + j] = ar[i][j] + eb1[tx * 8 + j];
                Hcol[(size_t)n * HID + tx * 8 + j] = ac[i][j];
            }
        }
    }
}

// MFMA edge kernel over SORTED edges (R8 best-measured config, bound 8).
__global__ __launch_bounds__(256, 8) void k_edge_mfma(
    const float* __restrict__ Hrow, const float* __restrict__ Hcol,
    const float* __restrict__ x,
    const int* __restrict__ srow, const int* __restrict__ scol,
    const float* __restrict__ sea,
    const float* __restrict__ ew1_tail,
    const unsigned short* __restrict__ w2p, const float* __restrict__ eb2,
    const float* __restrict__ aw, const float* __restrict__ ab,
    const unsigned short* __restrict__ c1p, const float* __restrict__ cb1,
    const float* __restrict__ cw2,
    float* __restrict__ aggh, float* __restrict__ aggx, int E)
{
    __shared__ __align__(16) unsigned short tHi[2][16][136];
    __shared__ __align__(16) unsigned short tLo[2][16][136];
    __shared__ float sGate[2][2][16];
    __shared__ float sCD[32][4];
    __shared__ float sEA[32][2];
    __shared__ int sRow[32], sCol[32];

    const int t = threadIdx.x;
    const int wv = t >> 6, lane = t & 63;
    const int grp = wv >> 1, hf = wv & 1;
    const int quad = lane >> 4, ln = lane & 15;
    const int e0 = blockIdx.x * 32;

    if (lane < 16) {
        int eg = e0 + grp * 16 + lane;
        int ec = eg < E ? eg : E - 1;
        int r = srow[ec], c = scol[ec];
        sRow[grp * 16 + lane] = r; sCol[grp * 16 + lane] = c;
        float dx = x[r * 3 + 0] - x[c * 3 + 0];
        float dy = x[r * 3 + 1] - x[c * 3 + 1];
        float dz = x[r * 3 + 2] - x[c * 3 + 2];
        sCD[grp * 16 + lane][0] = dx;
        sCD[grp * 16 + lane][1] = dy;
        sCD[grp * 16 + lane][2] = dz;
        sCD[grp * 16 + lane][3] = dx * dx + dy * dy + dz * dz;
        sEA[grp * 16 + lane][0] = sea[(size_t)ec * 2 + 0];
        sEA[grp * 16 + lane][1] = sea[(size_t)ec * 2 + 1];
    }

    const int eM = grp * 16 + ln;
    const int rn = sRow[eM], cn = sCol[eM];
    const float rad = sCD[eM][3], ea0 = sEA[eM][0], ea1 = sEA[eM][1];

    // ---- phase 1: e_act (fused GEMM1) for this wave's channel half; edge = ln
#pragma unroll
    for (int kk = 0; kk < 2; ++kk) {
        const int kc = hf * 2 + kk;
        const int fb = kc * 32 + quad * 8;
        f32x4 a0 = *(const f32x4*)(Hrow + (size_t)rn * HID + fb);
        f32x4 a1 = *(const f32x4*)(Hrow + (size_t)rn * HID + fb + 4);
        f32x4 c0 = *(const f32x4*)(Hcol + (size_t)cn * HID + fb);
        f32x4 c1 = *(const f32x4*)(Hcol + (size_t)cn * HID + fb + 4);
        f32x4 w60 = *(const f32x4*)(ew1_tail + fb);
        f32x4 w61 = *(const f32x4*)(ew1_tail + fb + 4);
        f32x4 w70 = *(const f32x4*)(ew1_tail + 128 + fb);
        f32x4 w71 = *(const f32x4*)(ew1_tail + 128 + fb + 4);
        f32x4 w80 = *(const f32x4*)(ew1_tail + 256 + fb);
        f32x4 w81 = *(const f32x4*)(ew1_tail + 256 + fb + 4);
        bf16x8 ahi, alo;
#pragma unroll
        for (int j = 0; j < 4; ++j) {
            float s0 = a0[j] + c0[j] + rad * w60[j] + ea0 * w70[j] + ea1 * w80[j];
            float s1 = a1[j] + c1[j] + rad * w61[j] + ea0 * w71[j] + ea1 * w81[j];
            s0 = silu_f(s0);
            s1 = silu_f(s1);
            unsigned short h0 = bf16hi(s0), h1 = bf16hi(s1);
            ahi[j] = (short)h0;
            ahi[j + 4] = (short)h1;
            alo[j] = (short)bf16hi(s0 - bf16tof(h0));
            alo[j + 4] = (short)bf16hi(s1 - bf16tof(h1));
        }
        *(bf16x8*)&tHi[grp][ln][fb] = ahi;
        *(bf16x8*)&tLo[grp][ln][fb] = alo;
    }
    __syncthreads();   // barrier A

    bf16x8 g1hi[4], g1lo[4];
#pragma unroll
    for (int kc = 0; kc < 4; ++kc) {
        g1hi[kc] = *(const bf16x8*)&tHi[grp][ln][kc * 32 + quad * 8];
        g1lo[kc] = *(const bf16x8*)&tLo[grp][ln][kc * 32 + quad * 8];
    }

    f32x4 acc2[4];
#pragma unroll
    for (int i = 0; i < 4; ++i) acc2[i] = (f32x4){0.f, 0.f, 0.f, 0.f};
#pragma unroll
    for (int t8l = 0; t8l < 4; ++t8l) {
        const int t8 = hf * 4 + t8l;
        const unsigned short* bg = w2p + quad * 2048 + ln * 8 + t8 * 128;
#pragma unroll
        for (int kc = 0; kc < 4; ++kc) {
            bf16x8 bhi = *(const bf16x8*)(bg + kc * 8192);
            bf16x8 blo = *(const bf16x8*)(bg + kc * 8192 + 1024);
            acc2[t8l] = __builtin_amdgcn_mfma_f32_16x16x32_bf16(g1hi[kc], bhi, acc2[t8l], 0, 0, 0);
            acc2[t8l] = __builtin_amdgcn_mfma_f32_16x16x32_bf16(g1lo[kc], bhi, acc2[t8l], 0, 0, 0);
            acc2[t8l] = __builtin_amdgcn_mfma_f32_16x16x32_bf16(g1hi[kc], blo, acc2[t8l], 0, 0, 0);
        }
    }

    float pr[4] = {0.f, 0.f, 0.f, 0.f};
#pragma unroll
    for (int t8l = 0; t8l < 4; ++t8l) {
        int n = (hf * 4 + t8l) * 16 + ln;
        float bb = eb2[n], awn = aw[n];
#pragma unroll
        for (int r = 0; r < 4; ++r) {
            float v = silu_f(acc2[t8l][r] + bb);
            acc2[t8l][r] = v;
            pr[r] += v * awn;
        }
    }
#pragma unroll
    for (int r = 0; r < 4; ++r) {
        float p = pr[r];
        p += __shfl_xor(p, 1);
        p += __shfl_xor(p, 2);
        p += __shfl_xor(p, 4);
        p += __shfl_xor(p, 8);
        pr[r] = p;
    }
    if (ln == 0) {
#pragma unroll
        for (int r = 0; r < 4; ++r) sGate[grp][hf][quad * 4 + r] = pr[r];
    }
    __syncthreads();   // barrier B

    float gate[4];
    {
        float ab0 = ab[0];
#pragma unroll
        for (int r = 0; r < 4; ++r)
            gate[r] = sigmoid_f(sGate[grp][0][quad * 4 + r] +
                                sGate[grp][1][quad * 4 + r] + ab0);
    }

#pragma unroll
    for (int t8l = 0; t8l < 4; ++t8l) {
        int n = (hf * 4 + t8l) * 16 + ln;
#pragma unroll
        for (int r = 0; r < 4; ++r) {
            float v = acc2[t8l][r] * gate[r];
            acc2[t8l][r] = v;
            unsigned short hi = bf16hi(v);
            float rem = v - bf16tof(hi);
            tHi[grp][quad * 4 + r][n] = hi;
            tLo[grp][quad * 4 + r][n] = bf16hi(rem);
        }
    }

    {
        int i = 0;
        while (i < 16) {
            int node = sRow[grp * 16 + i];
            int j = i + 1;
            while (j < 16 && sRow[grp * 16 + j] == node) ++j;
#pragma unroll
            for (int t8l = 0; t8l < 4; ++t8l) {
                float s = 0.f;
#pragma unroll
                for (int r = 0; r < 4; ++r) {
                    int el = quad * 4 + r;
                    bool ok = (el >= i) && (el < j) && (e0 + grp * 16 + el < E);
                    s += ok ? acc2[t8l][r] : 0.f;
                }
                s += __shfl_xor(s, 16);
                s += __shfl_xor(s, 32);
                if (quad == (t8l & 3))
                    atomicAdd(&aggh[(size_t)node * HID + (hf * 4 + t8l) * 16 + ln], s);
            }
            i = j;
        }
    }
    __syncthreads();   // barrier C

    bf16x8 g3hi[4], g3lo[4];
#pragma unroll
    for (int kc = 0; kc < 4; ++kc) {
        g3hi[kc] = *(const bf16x8*)&tHi[grp][ln][kc * 32 + quad * 8];
        g3lo[kc] = *(const bf16x8*)&tLo[grp][ln][kc * 32 + quad * 8];
    }
    f32x4 acc3[4];
#pragma unroll
    for (int i = 0; i < 4; ++i) acc3[i] = (f32x4){0.f, 0.f, 0.f, 0.f};
#pragma unroll
    for (int t8l = 0; t8l < 4; ++t8l) {
        const int t8 = hf * 4 + t8l;
        const unsigned short* bg = c1p + quad * 2048 + ln * 8 + t8 * 128;
#pragma unroll
        for (int kc = 0; kc < 4; ++kc) {
            bf16x8 bhi = *(const bf16x8*)(bg + kc * 8192);
            bf16x8 blo = *(const bf16x8*)(bg + kc * 8192 + 1024);
            acc3[t8l] = __builtin_amdgcn_mfma_f32_16x16x32_bf16(g3hi[kc], bhi, acc3[t8l], 0, 0, 0);
            acc3[t8l] = __builtin_amdgcn_mfma_f32_16x16x32_bf16(g3lo[kc], bhi, acc3[t8l], 0, 0, 0);
            acc3[t8l] = __builtin_amdgcn_mfma_f32_16x16x32_bf16(g3hi[kc], blo, acc3[t8l], 0, 0, 0);
        }
    }
    {
        float pr3[4] = {0.f, 0.f, 0.f, 0.f};
#pragma unroll
        for (int t8l = 0; t8l < 4; ++t8l) {
            int n = (hf * 4 + t8l) * 16 + ln;
            float bb = cb1[n], cwn = cw2[n];
#pragma unroll
            for (int r = 0; r < 4; ++r) {
                float u = silu_f(acc3[t8l][r] + bb);
                pr3[r] += u * cwn;
            }
        }
#pragma unroll
        for (int r = 0; r < 4; ++r) {
            float p = pr3[r];
            p += __shfl_xor(p, 1);
            p += __shfl_xor(p, 2);
            p += __shfl_xor(p, 4);
            p += __shfl_xor(p, 8);
            pr3[r] = p;
        }
        int i = 0;
        while (i < 16) {
            int node = sRow[grp * 16 + i];
            int j = i + 1;
            while (j < 16 && sRow[grp * 16 + j] == node) ++j;
            float s = 0.f;
            if (ln < 3) {
#pragma unroll
                for (int r = 0; r < 4; ++r) {
                    int el = quad * 4 + r;
                    int m = grp * 16 + el;
                    bool ok = (el >= i) && (el < j) && (e0 + m < E);
                    s += ok ? sCD[m][ln] * pr3[r] : 0.f;
                }
            }
            s += __shfl_xor(s, 16);
            s += __shfl_xor(s, 32);
            if (quad == 0 && ln < 3)
                atomicAdd(&aggx[node * 3 + ln], s);
            i = j;
        }
    }
}

// MFMA node kernel: 16 nodes/block, 4 waves; wave wv owns output channels
// [wv*32, wv*32+32). Two shared split-bf16 [16][128] tiles (h/act in t0,
// agg/h_new in t1). Fuses vel+x update (zeroing aggx), aggh zeroing, node MLP,
// and next-layer Hrow/Hcol (hpre, eb1 folded). Fragment conventions identical
// to k_edge_mfma (row index = first tile index = ln; C row=quad*4+r, col=ln).
__global__ __launch_bounds__(256, 4) void k_node_mfma(
    float* __restrict__ h, float* __restrict__ aggh,
    float* __restrict__ aggx, const int* __restrict__ cnti,
    float* __restrict__ x, float* __restrict__ vel,
    const unsigned short* __restrict__ v1p, const float* __restrict__ vb1,
    const float* __restrict__ vw2, const float* __restrict__ vb2,
    const unsigned short* __restrict__ n1ap, const unsigned short* __restrict__ n1bp,
    const float* __restrict__ nb1,
    const unsigned short* __restrict__ n2p, const float* __restrict__ nb2,
    const unsigned short* __restrict__ hrp, const unsigned short* __restrict__ hcp,
    const float* __restrict__ eb1n,
    float* __restrict__ Hrow, float* __restrict__ Hcol, int N, int last)
{
    __shared__ __align__(16) unsigned short t0Hi[16][136], t0Lo[16][136];
    __shared__ __align__(16) unsigned short t1Hi[16][136], t1Lo[16][136];
    __shared__ float sVel[4][16];

    const int t = threadIdx.x;
    const int wv = t >> 6, lane = t & 63;
    const int quad = lane >> 4, ln = lane & 15;
    const int n0 = blockIdx.x * 16;

    // ---- build h-tile (t0) and agg-tile (t1); zero aggh after read
    {
        int node = t >> 4, kb = (t & 15) * 8;
        int n = n0 + node;
        int nc = n < N ? n : N - 1;
        f32x4 a0 = *(const f32x4*)&h[(size_t)nc * HID + kb];
        f32x4 a1 = *(const f32x4*)&h[(size_t)nc * HID + kb + 4];
        f32x4 g0 = *(const f32x4*)&aggh[(size_t)nc * HID + kb];
        f32x4 g1 = *(const f32x4*)&aggh[(size_t)nc * HID + kb + 4];
        if (n < N) {
            *(f32x4*)&aggh[(size_t)n * HID + kb]     = (f32x4){0.f, 0.f, 0.f, 0.f};
            *(f32x4*)&aggh[(size_t)n * HID + kb + 4] = (f32x4){0.f, 0.f, 0.f, 0.f};
        }
        bf16x8 hh, hl, gh, gl;
#pragma unroll
        for (int j = 0; j < 4; ++j) {
            unsigned short u0 = bf16hi(a0[j]);
            unsigned short u1 = bf16hi(a1[j]);
            hh[j] = (short)u0; hh[j + 4] = (short)u1;
            hl[j] = (short)bf16hi(a0[j] - bf16tof(u0));
            hl[j + 4] = (short)bf16hi(a1[j] - bf16tof(u1));
            unsigned short v0 = bf16hi(g0[j]);
            unsigned short v1 = bf16hi(g1[j]);
            gh[j] = (short)v0; gh[j + 4] = (short)v1;
            gl[j] = (short)bf16hi(g0[j] - bf16tof(v0));
            gl[j + 4] = (short)bf16hi(g1[j] - bf16tof(v1));
        }
        *(bf16x8*)&t0Hi[node][kb] = hh;
        *(bf16x8*)&t0Lo[node][kb] = hl;
        *(bf16x8*)&t1Hi[node][kb] = gh;
        *(bf16x8*)&t1Lo[node][kb] = gl;
    }
    __syncthreads();   // tiles ready

    // ---- A-fragments from h-tile
    bf16x8 ahi[4], alo[4];
#pragma unroll
    for (int kc = 0; kc < 4; ++kc) {
        ahi[kc] = *(const bf16x8*)&t0Hi[ln][kc * 32 + quad * 8];
        alo[kc] = *(const bf16x8*)&t0Lo[ln][kc * 32 + quad * 8];
    }

    // ---- vel GEMM (this wave's 32 channels)
    f32x4 av[2];
    av[0] = (f32x4){0.f, 0.f, 0.f, 0.f};
    av[1] = (f32x4){0.f, 0.f, 0.f, 0.f};
#pragma unroll
    for (int t8g = 0; t8g < 2; ++t8g) {
        const unsigned short* bg = v1p + quad * 2048 + ln * 8 + (wv * 2 + t8g) * 128;
#pragma unroll
        for (int kc = 0; kc < 4; ++kc) {
            bf16x8 bhi = *(const bf16x8*)(bg + kc * 8192);
            bf16x8 blo = *(const bf16x8*)(bg + kc * 8192 + 1024);
            av[t8g] = __builtin_amdgcn_mfma_f32_16x16x32_bf16(ahi[kc], bhi, av[t8g], 0, 0, 0);
            av[t8g] = __builtin_amdgcn_mfma_f32_16x16x32_bf16(alo[kc], bhi, av[t8g], 0, 0, 0);
            av[t8g] = __builtin_amdgcn_mfma_f32_16x16x32_bf16(ahi[kc], blo, av[t8g], 0, 0, 0);
        }
    }
    {
        float pv[4] = {0.f, 0.f, 0.f, 0.f};
#pragma unroll
        for (int t8g = 0; t8g < 2; ++t8g) {
            int ch = wv * 32 + t8g * 16 + ln;
            float b1 = vb1[ch], w2 = vw2[ch];
#pragma unroll
            for (int r = 0; r < 4; ++r)
                pv[r] += silu_f(av[t8g][r] + b1) * w2;
        }
#pragma unroll
        for (int r = 0; r < 4; ++r) {
            float p = pv[r];
            p += __shfl_xor(p, 1);
            p += __shfl_xor(p, 2);
            p += __shfl_xor(p, 4);
            p += __shfl_xor(p, 8);
            pv[r] = p;
        }
        if (ln == 0) {
#pragma unroll
            for (int r = 0; r < 4; ++r) sVel[wv][quad * 4 + r] = pv[r];
        }
    }

    // ---- n1: A=h (t0 frags) x n1ap, then A=agg (t1 frags) x n1bp
    f32x4 n1acc[2];
    n1acc[0] = (f32x4){0.f, 0.f, 0.f, 0.f};
    n1acc[1] = (f32x4){0.f, 0.f, 0.f, 0.f};
#pragma unroll
    for (int t8g = 0; t8g < 2; ++t8g) {
        const unsigned short* bg = n1ap + quad * 2048 + ln * 8 + (wv * 2 + t8g) * 128;
#pragma unroll
        for (int kc = 0; kc < 4; ++kc) {
            bf16x8 bhi = *(const bf16x8*)(bg + kc * 8192);
            bf16x8 blo = *(const bf16x8*)(bg + kc * 8192 + 1024);
            n1acc[t8g] = __builtin_amdgcn_mfma_f32_16x16x32_bf16(ahi[kc], bhi, n1acc[t8g], 0, 0, 0);
            n1acc[t8g] = __builtin_amdgcn_mfma_f32_16x16x32_bf16(alo[kc], bhi, n1acc[t8g], 0, 0, 0);
            n1acc[t8g] = __builtin_amdgcn_mfma_f32_16x16x32_bf16(ahi[kc], blo, n1acc[t8g], 0, 0, 0);
        }
    }
#pragma unroll
    for (int kc = 0; kc < 4; ++kc) {
        ahi[kc] = *(const bf16x8*)&t1Hi[ln][kc * 32 + quad * 8];
        alo[kc] = *(const bf16x8*)&t1Lo[ln][kc * 32 + quad * 8];
    }
#pragma unroll
    for (int t8g = 0; t8g < 2; ++t8g) {
        const unsigned short* bg = n1bp + quad * 2048 + ln * 8 + (wv * 2 + t8g) * 128;
#pragma unroll
        for (int kc = 0; kc < 4; ++kc) {
            bf16x8 bhi = *(const bf16x8*)(bg + kc * 8192);
            bf16x8 blo = *(const bf16x8*)(bg + kc * 8192 + 1024);
            n1acc[t8g] = __builtin_amdgcn_mfma_f32_16x16x32_bf16(ahi[kc], bhi, n1acc[t8g], 0, 0, 0);
            n1acc[t8g] = __builtin_amdgcn_mfma_f32_16x16x32_bf16(alo[kc], bhi, n1acc[t8g], 0, 0, 0);
            n1acc[t8g] = __builtin_amdgcn_mfma_f32_16x16x32_bf16(ahi[kc], blo, n1acc[t8g], 0, 0, 0);
        }
    }
    __syncthreads();   // sVel ready; all t0/t1 fragment reads done

    // ---- vel/x update (wave0 lanes 0..15, one node each); zero aggx
    if (t < 16) {
        int n = n0 + t;
        if (n < N) {
            float vs = sVel[0][t] + sVel[1][t] + sVel[2][t] + sVel[3][t] + vb2[0];
            float cc = fmaxf((float)cnti[n], 1.0f);
#pragma unroll
            for (int d = 0; d < 3; ++d) {
                float vn = vs * vel[n * 3 + d];
                float xn = x[n * 3 + d] + aggx[n * 3 + d] / cc + vn;
                vel[n * 3 + d] = vn;
                x[n * 3 + d] = xn;
                aggx[n * 3 + d] = 0.f;
            }
        }
    }

    // ---- act = silu(n1 + nb1); write split into t0 (overwrites h-tile)
#pragma unroll
    for (int t8g = 0; t8g < 2; ++t8g) {
        int ch = wv * 32 + t8g * 16 + ln;
        float bb = nb1[ch];
#pragma unroll
        for (int r = 0; r < 4; ++r) {
            float v = silu_f(n1acc[t8g][r] + bb);
            unsigned short hi = bf16hi(v);
            t0Hi[quad * 4 + r][ch] = hi;
            t0Lo[quad * 4 + r][ch] = bf16hi(v - bf16tof(hi));
        }
    }
    __syncthreads();   // act tile complete

    // ---- n2: h_new = act @ nw2 + nb2; store h; build h_new tile in t1
#pragma unroll
    for (int kc = 0; kc < 4; ++kc) {
        ahi[kc] = *(const bf16x8*)&t0Hi[ln][kc * 32 + quad * 8];
        alo[kc] = *(const bf16x8*)&t0Lo[ln][kc * 32 + quad * 8];
    }
    f32x4 n2acc[2];
    n2acc[0] = (f32x4){0.f, 0.f, 0.f, 0.f};
    n2acc[1] = (f32x4){0.f, 0.f, 0.f, 0.f};
#pragma unroll
    for (int t8g = 0; t8g < 2; ++t8g) {
        const unsigned short* bg = n2p + quad * 2048 + ln * 8 + (wv * 2 + t8g) * 128;
#pragma unroll
        for (int kc = 0; kc < 4; ++kc) {
            bf16x8 bhi = *(const bf16x8*)(bg + kc * 8192);
            bf16x8 blo = *(const bf16x8*)(bg + kc * 8192 + 1024);
            n2acc[t8g] = __builtin_amdgcn_mfma_f32_16x16x32_bf16(ahi[kc], bhi, n2acc[t8g], 0, 0, 0);
            n2acc[t8g] = __builtin_amdgcn_mfma_f32_16x16x32_bf16(alo[kc], bhi, n2acc[t8g], 0, 0, 0);
            n2acc[t8g] = __builtin_amdgcn_mfma_f32_16x16x32_bf16(ahi[kc], blo, n2acc[t8g], 0, 0, 0);
        }
    }
#pragma unroll
    for (int t8g = 0; t8g < 2; ++t8g) {
        int ch = wv * 32 + t8g * 16 + ln;
        float bb = nb2[ch];
#pragma unroll
        for (int r = 0; r < 4; ++r) {
            int node = quad * 4 + r;
            int n = n0 + node;
            float v = n2acc[t8g][r] + bb;
            unsigned short hi = bf16hi(v);
            t1Hi[node][ch] = hi;
            t1Lo[node][ch] = bf16hi(v - bf16tof(hi));
            if (n < N) h[(size_t)n * HID + ch] = v;
        }
    }
    if (last) return;
    __syncthreads();   // h_new tile complete

    // ---- fused hpre: [Hrow|Hcol] = h_new @ ew1n (K=128, N=256); eb1n into Hrow
#pragma unroll
    for (int kc = 0; kc < 4; ++kc) {
        ahi[kc] = *(const bf16x8*)&t1Hi[ln][kc * 32 + quad * 8];
        alo[kc] = *(const bf16x8*)&t1Lo[ln][kc * 32 + quad * 8];
    }
    const unsigned short* mat = (wv < 2) ? hrp : hcp;
    float* outg = (wv < 2) ? Hrow : Hcol;
    const bool isrow = (wv < 2);
    const int half = wv & 1;
    f32x4 hacc[4];
#pragma unroll
    for (int i = 0; i < 4; ++i) hacc[i] = (f32x4){0.f, 0.f, 0.f, 0.f};
#pragma unroll
    for (int t8g = 0; t8g < 4; ++t8g) {
        const unsigned short* bg = mat + quad * 2048 + ln * 8 + (half * 4 + t8g) * 128;
#pragma unroll
        for (int kc = 0; kc < 4; ++kc) {
            bf16x8 bhi = *(const bf16x8*)(bg + kc * 8192);
            bf16x8 blo = *(const bf16x8*)(bg + kc * 8192 + 1024);
            hacc[t8g] = __builtin_amdgcn_mfma_f32_16x16x32_bf16(ahi[kc], bhi, hacc[t8g], 0, 0, 0);
            hacc[t8g] = __builtin_amdgcn_mfma_f32_16x16x32_bf16(alo[kc], bhi, hacc[t8g], 0, 0, 0);
            hacc[t8g] = __builtin_amdgcn_mfma_f32_16x16x32_bf16(ahi[kc], blo, hacc[t8g], 0, 0, 0);
        }
    }
#pragma unroll
    for (int t8g = 0; t8g < 4; ++t8g) {
        int ch = half * 64 + t8g * 16 + ln;
        float bb = isrow ? eb1n[ch] : 0.f;
#pragma unroll
        for (int r = 0; r < 4; ++r) {
            int n = n0 + quad * 4 + r;
            if (n < N) outg[(size_t)n * HID + ch] = hacc[t8g][r] + bb;
        }
    }
}

__global__ void k_proj(const float* __restrict__ h, const float* __restrict__ pw,
                       const float* __restrict__ pb, float* __restrict__ out, int N) {
    int idx = blockIdx.x * 256 + threadIdx.x;
    if (idx >= N * 3) return;
    int n = idx / 3, p = idx % 3;
    float s = pb[p];
    const float* hr = &h[(size_t)n * HID];
#pragma unroll 8
    for (int k = 0; k < HID; ++k) s += hr[k] * pw[k * 3 + p];
    out[idx] = s;
}

extern "C" void kernel_launch(void* const* d_in, const int* in_sizes, int n_in,
                              void* d_out, int out_size, void* d_ws, size_t ws_size,
                              hipStream_t stream)
{
    const float* h_in  = (const float*)d_in[0];
    const float* x_in  = (const float*)d_in[1];
    const float* v_in  = (const float*)d_in[2];
    const float* eattr = (const float*)d_in[3];
    const int*   edges = (const int*)d_in[4];
    const float* emb_w = (const float*)d_in[5];
    const float* emb_b = (const float*)d_in[6];
    const float* ew1   = (const float*)d_in[7];
    const float* eb1   = (const float*)d_in[8];
    const float* ew2   = (const float*)d_in[9];
    const float* eb2   = (const float*)d_in[10];
    const float* aw    = (const float*)d_in[11];
    const float* ab    = (const float*)d_in[12];
    const float* nw1   = (const float*)d_in[13];
    const float* nb1   = (const float*)d_in[14];
    const float* nw2   = (const float*)d_in[15];
    const float* nb2   = (const float*)d_in[16];
    const float* cw1   = (const float*)d_in[17];
    const float* cb1   = (const float*)d_in[18];
    const float* cw2   = (const float*)d_in[19];
    const float* vw1   = (const float*)d_in[20];
    const float* vb1   = (const float*)d_in[21];
    const float* vw2   = (const float*)d_in[22];
    const float* vb2   = (const float*)d_in[23];
    const float* pw    = (const float*)d_in[24];
    const float* pb    = (const float*)d_in[25];

    const int N = in_sizes[0] / 6;
    const int E = in_sizes[4] / 2;
    const int* rows = edges;
    const int* cols = edges + E;

    float* ws   = (float*)d_ws;
    float* hbuf = ws;  ws += (size_t)N * HID;
    float* aggh = ws;  ws += (size_t)N * HID;
    float* aggx = ws;  ws += (size_t)N * 3;
    float* xb   = ws;  ws += (size_t)N * 3;
    float* vb   = ws;  ws += (size_t)N * 3;
    float* sea  = ws;  ws += (size_t)E * 2;
    float* Hrow = ws;  ws += (size_t)N * HID;
    float* Hcol = ws;  ws += (size_t)N * HID;
    int* wi = (int*)ws;
    int* cnti = wi;  wi += N;
    int* basei = wi; wi += N;
    int* fill = wi;  wi += N;
    int* srow = wi;  wi += E;
    int* scol = wi;  wi += E;
    unsigned short* us = (unsigned short*)wi;
    unsigned short* w2p  = us;  us += 4 * 32768;
    unsigned short* c1p  = us;  us += 4 * 32768;
    unsigned short* v1p  = us;  us += 4 * 32768;
    unsigned short* n1ap = us;  us += 4 * 32768;
    unsigned short* n1bp = us;  us += 4 * 32768;
    unsigned short* n2p  = us;  us += 4 * 32768;
    unsigned short* hrp  = us;  us += 4 * 32768;
    unsigned short* hcp  = us;  us += 4 * 32768;
    float* outp = (float*)d_out;

    hipMemcpyAsync(xb, x_in, (size_t)N * 3 * sizeof(float), hipMemcpyDeviceToDevice, stream);
    hipMemcpyAsync(vb, v_in, (size_t)N * 3 * sizeof(float), hipMemcpyDeviceToDevice, stream);
    hipMemsetAsync(cnti, 0, 2 * N * sizeof(int), stream);  // cnti+basei; fill separate
    hipMemsetAsync(fill, 0, N * sizeof(int), stream);
    hipMemsetAsync(aggh, 0, (size_t)N * HID * sizeof(float), stream);  // layer 0 only;
    hipMemsetAsync(aggx, 0, (size_t)N * 3 * sizeof(float), stream);    // k_node re-zeroes
    k_cnt<<<(E + 255) / 256, 256, 0, stream>>>(rows, cnti, E);
    k_scan<<<1, 256, 0, stream>>>(cnti, basei, N);
    k_scatter<<<(E + 255) / 256, 256, 0, stream>>>(rows, cols, eattr, basei, fill,
                                                   srow, scol, sea, E);
    k_pack_w<<<(4 * 32768 + 255) / 256, 256, 0, stream>>>(ew2, cw1, w2p, c1p);
    k_pack_node<<<(4 * 6 * 16384 + 255) / 256, 256, 0, stream>>>(
        vw1, nw1, nw2, ew1, v1p, n1ap, n1bp, n2p, hrp, hcp);
    k_embed<<<(N * HID + 255) / 256, 256, 0, stream>>>(h_in, emb_w, emb_b, hbuf, N);
    k_hpre<<<(N + 63) / 64, 256, 0, stream>>>(hbuf, ew1, eb1, Hrow, Hcol, N);

    for (int l = 0; l < 4; ++l) {
        k_edge_mfma<<<(E + 31) / 32, 256, 0, stream>>>(
            Hrow, Hcol, xb, srow, scol, sea,
            ew1 + (size_t)l * 33152 + 256 * HID,
            w2p + (size_t)l * 32768, eb2 + l * HID,
            aw + l * HID, ab + l,
            c1p + (size_t)l * 32768, cb1 + l * HID, cw2 + l * HID,
            aggh, aggx, E);
        int nl = l + 1;
        k_node_mfma<<<(N + 15) / 16, 256, 0, stream>>>(
            hbuf, aggh, aggx, cnti, xb, vb,
            v1p + (size_t)l * 32768, vb1 + l * HID, vw2 + l * HID, vb2 + l,
            n1ap + (size_t)l * 32768, n1bp + (size_t)l * 32768, nb1 + l * HID,
            n2p + (size_t)l * 32768, nb2 + l * HID,
            hrp + (size_t)(l < 3 ? nl : 0) * 32768,
            hcp + (size_t)(l < 3 ? nl : 0) * 32768,
            eb1 + (size_t)(l < 3 ? nl : 0) * HID,
            Hrow, Hcol, N, (l == 3) ? 1 : 0);
    }
    k_proj<<<(N * 3 + 255) / 256, 256, 0, stream>>>(hbuf, pw, pb, outp, N);
    hipMemcpyAsync(outp + (size_t)N * 3, xb, (size_t)N * 3 * sizeof(float), hipMemcpyDeviceToDevice, stream);
    hipMemcpyAsync(outp + (size_t)N * 6, vb, (size_t)N * 3 * sizeof(float), hipMemcpyDeviceToDevice, stream);
}

// Round 13
// 879.686 us; speedup vs baseline: 1.4670x; 1.0183x over previous
//
#include <hip/hip_runtime.h>
#include <math.h>

#define HID 128

typedef __attribute__((ext_vector_type(8))) short bf16x8;
typedef __attribute__((ext_vector_type(4))) float f32x4;

__device__ __forceinline__ float silu_f(float v) {
    return v * __builtin_amdgcn_rcpf(1.0f + __expf(-v));
}
__device__ __forceinline__ float sigmoid_f(float v) {
    return __builtin_amdgcn_rcpf(1.0f + __expf(-v));
}
__device__ __forceinline__ unsigned short bf16hi(float f) {
    return (unsigned short)(__float_as_uint(f) >> 16);
}
__device__ __forceinline__ float bf16tof(unsigned short u) {
    return __uint_as_float(((unsigned int)u) << 16);
}

// ---------- CSR / sort-by-row (rows static across layers; built once per call) ----------
__global__ void k_cnt(const int* __restrict__ rows, int* __restrict__ cnti, int E) {
    int i = blockIdx.x * 256 + threadIdx.x;
    if (i < E) atomicAdd(&cnti[rows[i]], 1);
}

// single-block exclusive scan over N counts -> base
__global__ void k_scan(const int* __restrict__ cnti, int* __restrict__ base, int N) {
    __shared__ int part[256];
    int t = threadIdx.x;
    int chunk = (N + 255) / 256;
    int lo = t * chunk, hi = lo + chunk < N ? lo + chunk : N;
    int s = 0;
    for (int i = lo; i < hi; ++i) s += cnti[i];
    part[t] = s;
    __syncthreads();
    for (int off = 1; off < 256; off <<= 1) {
        int v = (t >= off) ? part[t - off] : 0;
        __syncthreads();
        part[t] += v;
        __syncthreads();
    }
    int run = (t == 0) ? 0 : part[t - 1];
    for (int i = lo; i < hi; ++i) { base[i] = run; run += cnti[i]; }
}

__global__ void k_scatter(const int* __restrict__ rows, const int* __restrict__ cols,
                          const float* __restrict__ eattr,
                          const int* __restrict__ base, int* __restrict__ fill,
                          int* __restrict__ srow, int* __restrict__ scol,
                          float* __restrict__ sea, int E) {
    int e = blockIdx.x * 256 + threadIdx.x;
    if (e >= E) return;
    int r = rows[e];
    int pos = base[r] + atomicAdd(&fill[r], 1);
    srow[pos] = r;
    scol[pos] = cols[e];
    sea[pos * 2 + 0] = eattr[(size_t)e * 2 + 0];
    sea[pos * 2 + 1] = eattr[(size_t)e * 2 + 1];
}

__global__ void k_embed(const float* __restrict__ hin, const float* __restrict__ w,
                        const float* __restrict__ b, float* __restrict__ hout, int N) {
    int idx = blockIdx.x * 256 + threadIdx.x;
    if (idx >= N * HID) return;
    int n = idx >> 7, j = idx & 127;
    float s = b[j];
    const float* hr = &hin[n * 6];
#pragma unroll
    for (int k = 0; k < 6; ++k) s += hr[k] * w[k * HID + j];
    hout[idx] = s;
}

// pack weights for MFMA (hi/lo split): s-block = [hi 1024 | lo 1024], entry n*8 + (k&7)
__global__ void k_pack_w(const float* __restrict__ ew2, const float* __restrict__ cw1,
                         unsigned short* __restrict__ w2p, unsigned short* __restrict__ c1p) {
    int idx = blockIdx.x * 256 + threadIdx.x;
    if (idx >= 4 * 32768) return;
    int l = idx >> 15, r = idx & 32767;
    const float* src;
    unsigned short* dst;
    int k, n;
    if (r < 16384) {
        k = r >> 7; n = r & 127;
        src = ew2 + (size_t)l * 16384 + k * 128 + n;
        dst = w2p + (size_t)l * 32768;
    } else {
        int rr = r - 16384; k = rr >> 7; n = rr & 127;
        src = cw1 + (size_t)l * 16384 + k * 128 + n;
        dst = c1p + (size_t)l * 32768;
    }
    float f = *src;
    unsigned short hi = bf16hi(f);
    float rem = f - bf16tof(hi);
    int s = k >> 3;
    int b = s * 2048 + n * 8 + (k & 7);
    dst[b] = hi;
    dst[b + 1024] = bf16hi(rem);
}

// pack node-phase weights: vw1 / nw1(two halves) / nw2 / ew1 rows 0:128, 128:256
// all as standard 128x128 K-major packed (same format as w2p).
__global__ void k_pack_node(const float* __restrict__ vw1, const float* __restrict__ nw1,
                            const float* __restrict__ nw2, const float* __restrict__ ew1,
                            unsigned short* __restrict__ v1p, unsigned short* __restrict__ n1ap,
                            unsigned short* __restrict__ n1bp, unsigned short* __restrict__ n2p,
                            unsigned short* __restrict__ hrp, unsigned short* __restrict__ hcp) {
    int idx = blockIdx.x * 256 + threadIdx.x;
    if (idx >= 4 * 6 * 16384) return;
    int l = idx / (6 * 16384);
    int r = idx % (6 * 16384);
    int m = r / 16384;
    int e = r % 16384;
    int k = e >> 7, n = e & 127;
    const float* src;
    unsigned short* dst;
    switch (m) {
        case 0: src = vw1 + (size_t)l * 16384 + k * 128 + n;            dst = v1p  + (size_t)l * 32768; break;
        case 1: src = nw1 + (size_t)l * 32768 + k * 128 + n;            dst = n1ap + (size_t)l * 32768; break;
        case 2: src = nw1 + (size_t)l * 32768 + (128 + k) * 128 + n;    dst = n1bp + (size_t)l * 32768; break;
        case 3: src = nw2 + (size_t)l * 16384 + k * 128 + n;            dst = n2p  + (size_t)l * 32768; break;
        case 4: src = ew1 + (size_t)l * 33152 + k * 128 + n;            dst = hrp  + (size_t)l * 32768; break;
        default: src = ew1 + (size_t)l * 33152 + (128 + k) * 128 + n;   dst = hcp  + (size_t)l * 32768; break;
    }
    float f = *src;
    unsigned short hi = bf16hi(f);
    float rem = f - bf16tof(hi);
    int s = k >> 3;
    int b = s * 2048 + n * 8 + (k & 7);
    dst[b] = hi;
    dst[b + 1024] = bf16hi(rem);
}

// per-node GEMM1 hoist: Hrow = h @ W[0:128] + eb1, Hcol = h @ W[128:256]  (fp32, exact)
// (used once after embedding; subsequent layers fuse this into k_node_mfma)
__global__ __launch_bounds__(256, 2) void k_hpre(
    const float* __restrict__ h, const float* __restrict__ w,
    const float* __restrict__ eb1,
    float* __restrict__ Hrow, float* __restrict__ Hcol, int N)
{
    __shared__ __align__(16) float BH[64][132];
    const int t = threadIdx.x;
    const int tx = t & 15, ty = t >> 4;
    const int n0 = blockIdx.x * 64;

    for (int idx = t; idx < 64 * 32; idx += 256) {
        int r = idx >> 5, c4 = idx & 31;
        int n = n0 + r;
        float4 v0 = make_float4(0.f, 0.f, 0.f, 0.f);
        if (n < N) v0 = *(const float4*)&h[(size_t)n * HID + c4 * 4];
        *(float4*)&BH[r][c4 * 4] = v0;
    }
    __syncthreads();

    float ar[4][8], ac[4][8];
#pragma unroll
    for (int i = 0; i < 4; ++i)
#pragma unroll
        for (int j = 0; j < 8; ++j) { ar[i][j] = 0.f; ac[i][j] = 0.f; }

    const float* wr = &w[tx * 8];
    const float* wc = &w[128 * HID + tx * 8];
#pragma unroll 4
    for (int k = 0; k < HID; ++k) {
        float4 r0 = *(const float4*)&wr[k * HID];
        float4 r1 = *(const float4*)&wr[k * HID + 4];
        float4 c0 = *(const float4*)&wc[k * HID];
        float4 c1 = *(const float4*)&wc[k * HID + 4];
        float rv[8] = {r0.x, r0.y, r0.z, r0.w, r1.x, r1.y, r1.z, r1.w};
        float cv[8] = {c0.x, c0.y, c0.z, c0.w, c1.x, c1.y, c1.z, c1.w};
        float av[4];
#pragma unroll
        for (int i = 0; i < 4; ++i) av[i] = BH[ty * 4 + i][k];
#pragma unroll
        for (int i = 0; i < 4; ++i)
#pragma unroll
            for (int j = 0; j < 8; ++j) {
                ar[i][j] += av[i] * rv[j];
                ac[i][j] += av[i] * cv[j];
            }
    }
#pragma unroll
    for (int i = 0; i < 4; ++i) {
        int n = n0 + ty * 4 + i;
        if (n < N) {
#pragma unroll
            for (int j = 0; j < 8; ++j) {
                Hrow[(size_t)n * HID + tx * 8 + j] = ar[i][j] + eb1[tx * 8 + j];
                Hcol[(size_t)n * HID + tx * 8 + j] = ac[i][j];
            }
        }
    }
}

// MFMA edge kernel over SORTED edges: 32 edges/block, 4 waves = 2 groups x 2
// channel-half waves. GEMM2/GEMM3 use kc-outer fragment streaming (one A-pair
// live at a time) so peak VGPR fits the 64-reg cap at 8 blocks/CU with NO spill.
__global__ __launch_bounds__(256, 8) void k_edge_mfma(
    const float* __restrict__ Hrow, const float* __restrict__ Hcol,
    const float* __restrict__ x,
    const int* __restrict__ srow, const int* __restrict__ scol,
    const float* __restrict__ sea,
    const float* __restrict__ ew1_tail,
    const unsigned short* __restrict__ w2p, const float* __restrict__ eb2,
    const float* __restrict__ aw, const float* __restrict__ ab,
    const unsigned short* __restrict__ c1p, const float* __restrict__ cb1,
    const float* __restrict__ cw2,
    float* __restrict__ aggh, float* __restrict__ aggx, int E)
{
    __shared__ __align__(16) unsigned short tHi[2][16][136];
    __shared__ __align__(16) unsigned short tLo[2][16][136];
    __shared__ float sGate[2][2][16];
    __shared__ float sCD[32][4];
    __shared__ float sEA[32][2];
    __shared__ int sRow[32], sCol[32];

    const int t = threadIdx.x;
    const int wv = t >> 6, lane = t & 63;
    const int grp = wv >> 1, hf = wv & 1;
    const int quad = lane >> 4, ln = lane & 15;
    const int e0 = blockIdx.x * 32;

    if (lane < 16) {
        int eg = e0 + grp * 16 + lane;
        int ec = eg < E ? eg : E - 1;
        int r = srow[ec], c = scol[ec];
        sRow[grp * 16 + lane] = r; sCol[grp * 16 + lane] = c;
        float dx = x[r * 3 + 0] - x[c * 3 + 0];
        float dy = x[r * 3 + 1] - x[c * 3 + 1];
        float dz = x[r * 3 + 2] - x[c * 3 + 2];
        sCD[grp * 16 + lane][0] = dx;
        sCD[grp * 16 + lane][1] = dy;
        sCD[grp * 16 + lane][2] = dz;
        sCD[grp * 16 + lane][3] = dx * dx + dy * dy + dz * dz;
        sEA[grp * 16 + lane][0] = sea[(size_t)ec * 2 + 0];
        sEA[grp * 16 + lane][1] = sea[(size_t)ec * 2 + 1];
    }

    const int eM = grp * 16 + ln;
    const int rn = sRow[eM], cn = sCol[eM];
    const float rad = sCD[eM][3], ea0 = sEA[eM][0], ea1 = sEA[eM][1];

    // ---- phase 1: e_act (fused GEMM1) for this wave's channel half; edge = ln
#pragma unroll
    for (int kk = 0; kk < 2; ++kk) {
        const int kc = hf * 2 + kk;
        const int fb = kc * 32 + quad * 8;
        f32x4 a0 = *(const f32x4*)(Hrow + (size_t)rn * HID + fb);
        f32x4 a1 = *(const f32x4*)(Hrow + (size_t)rn * HID + fb + 4);
        f32x4 c0 = *(const f32x4*)(Hcol + (size_t)cn * HID + fb);
        f32x4 c1 = *(const f32x4*)(Hcol + (size_t)cn * HID + fb + 4);
        f32x4 w60 = *(const f32x4*)(ew1_tail + fb);
        f32x4 w61 = *(const f32x4*)(ew1_tail + fb + 4);
        f32x4 w70 = *(const f32x4*)(ew1_tail + 128 + fb);
        f32x4 w71 = *(const f32x4*)(ew1_tail + 128 + fb + 4);
        f32x4 w80 = *(const f32x4*)(ew1_tail + 256 + fb);
        f32x4 w81 = *(const f32x4*)(ew1_tail + 256 + fb + 4);
        bf16x8 ahi, alo;
#pragma unroll
        for (int j = 0; j < 4; ++j) {
            float s0 = a0[j] + c0[j] + rad * w60[j] + ea0 * w70[j] + ea1 * w80[j];
            float s1 = a1[j] + c1[j] + rad * w61[j] + ea0 * w71[j] + ea1 * w81[j];
            s0 = silu_f(s0);
            s1 = silu_f(s1);
            unsigned short h0 = bf16hi(s0), h1 = bf16hi(s1);
            ahi[j] = (short)h0;
            ahi[j + 4] = (short)h1;
            alo[j] = (short)bf16hi(s0 - bf16tof(h0));
            alo[j + 4] = (short)bf16hi(s1 - bf16tof(h1));
        }
        *(bf16x8*)&tHi[grp][ln][fb] = ahi;
        *(bf16x8*)&tLo[grp][ln][fb] = alo;
    }
    __syncthreads();   // barrier A: e_act tile complete

    // ---- GEMM2: kc-outer fragment streaming (one A-pair live at a time)
    f32x4 acc2[4];
#pragma unroll
    for (int i = 0; i < 4; ++i) acc2[i] = (f32x4){0.f, 0.f, 0.f, 0.f};
#pragma unroll
    for (int kc = 0; kc < 4; ++kc) {
        bf16x8 fhi = *(const bf16x8*)&tHi[grp][ln][kc * 32 + quad * 8];
        bf16x8 flo = *(const bf16x8*)&tLo[grp][ln][kc * 32 + quad * 8];
        const unsigned short* bgk = w2p + kc * 8192 + quad * 2048 + ln * 8 + hf * 512;
#pragma unroll
        for (int t8l = 0; t8l < 4; ++t8l) {
            bf16x8 bhi = *(const bf16x8*)(bgk + t8l * 128);
            bf16x8 blo = *(const bf16x8*)(bgk + t8l * 128 + 1024);
            acc2[t8l] = __builtin_amdgcn_mfma_f32_16x16x32_bf16(fhi, bhi, acc2[t8l], 0, 0, 0);
            acc2[t8l] = __builtin_amdgcn_mfma_f32_16x16x32_bf16(flo, bhi, acc2[t8l], 0, 0, 0);
            acc2[t8l] = __builtin_amdgcn_mfma_f32_16x16x32_bf16(fhi, blo, acc2[t8l], 0, 0, 0);
        }
    }

    // ---- silu + gate partial over this half's channels
    float pr[4] = {0.f, 0.f, 0.f, 0.f};
#pragma unroll
    for (int t8l = 0; t8l < 4; ++t8l) {
        int n = (hf * 4 + t8l) * 16 + ln;
        float bb = eb2[n], awn = aw[n];
#pragma unroll
        for (int r = 0; r < 4; ++r) {
            float v = silu_f(acc2[t8l][r] + bb);
            acc2[t8l][r] = v;
            pr[r] += v * awn;
        }
    }
#pragma unroll
    for (int r = 0; r < 4; ++r) {
        float p = pr[r];
        p += __shfl_xor(p, 1);
        p += __shfl_xor(p, 2);
        p += __shfl_xor(p, 4);
        p += __shfl_xor(p, 8);
        pr[r] = p;
    }
    if (ln == 0) {
#pragma unroll
        for (int r = 0; r < 4; ++r) sGate[grp][hf][quad * 4 + r] = pr[r];
    }
    __syncthreads();   // barrier B: gate partials ready; all e_act reads done

    float gate[4];
    {
        float ab0 = ab[0];
#pragma unroll
        for (int r = 0; r < 4; ++r)
            gate[r] = sigmoid_f(sGate[grp][0][quad * 4 + r] +
                                sGate[grp][1][quad * 4 + r] + ab0);
    }

    // ---- gate + write m (this half) into the tile (overwrites own e_act half)
#pragma unroll
    for (int t8l = 0; t8l < 4; ++t8l) {
        int n = (hf * 4 + t8l) * 16 + ln;
#pragma unroll
        for (int r = 0; r < 4; ++r) {
            float v = acc2[t8l][r] * gate[r];
            acc2[t8l][r] = v;                 // keep gated m (fp32) for agg_h
            unsigned short hi = bf16hi(v);
            float rem = v - bf16tof(hi);
            tHi[grp][quad * 4 + r][n] = hi;
            tLo[grp][quad * 4 + r][n] = bf16hi(rem);
        }
    }

    // ---- agg_h: run-segmented reduction (this half's channels, exact fp32)
    {
        int i = 0;
        while (i < 16) {
            int node = sRow[grp * 16 + i];
            int j = i + 1;
            while (j < 16 && sRow[grp * 16 + j] == node) ++j;
#pragma unroll
            for (int t8l = 0; t8l < 4; ++t8l) {
                float s = 0.f;
#pragma unroll
                for (int r = 0; r < 4; ++r) {
                    int el = quad * 4 + r;
                    bool ok = (el >= i) && (el < j) && (e0 + grp * 16 + el < E);
                    s += ok ? acc2[t8l][r] : 0.f;
                }
                s += __shfl_xor(s, 16);
                s += __shfl_xor(s, 32);
                if (quad == (t8l & 3))
                    atomicAdd(&aggh[(size_t)node * HID + (hf * 4 + t8l) * 16 + ln], s);
            }
            i = j;
        }
    }
    __syncthreads();   // barrier C: m tile complete

    // ---- GEMM3: kc-outer fragment streaming
    f32x4 acc3[4];
#pragma unroll
    for (int i = 0; i < 4; ++i) acc3[i] = (f32x4){0.f, 0.f, 0.f, 0.f};
#pragma unroll
    for (int kc = 0; kc < 4; ++kc) {
        bf16x8 fhi = *(const bf16x8*)&tHi[grp][ln][kc * 32 + quad * 8];
        bf16x8 flo = *(const bf16x8*)&tLo[grp][ln][kc * 32 + quad * 8];
        const unsigned short* bgk = c1p + kc * 8192 + quad * 2048 + ln * 8 + hf * 512;
#pragma unroll
        for (int t8l = 0; t8l < 4; ++t8l) {
            bf16x8 bhi = *(const bf16x8*)(bgk + t8l * 128);
            bf16x8 blo = *(const bf16x8*)(bgk + t8l * 128 + 1024);
            acc3[t8l] = __builtin_amdgcn_mfma_f32_16x16x32_bf16(fhi, bhi, acc3[t8l], 0, 0, 0);
            acc3[t8l] = __builtin_amdgcn_mfma_f32_16x16x32_bf16(flo, bhi, acc3[t8l], 0, 0, 0);
            acc3[t8l] = __builtin_amdgcn_mfma_f32_16x16x32_bf16(fhi, blo, acc3[t8l], 0, 0, 0);
        }
    }
    {
        float pr3[4] = {0.f, 0.f, 0.f, 0.f};
#pragma unroll
        for (int t8l = 0; t8l < 4; ++t8l) {
            int n = (hf * 4 + t8l) * 16 + ln;
            float bb = cb1[n], cwn = cw2[n];
#pragma unroll
            for (int r = 0; r < 4; ++r) {
                float u = silu_f(acc3[t8l][r] + bb);
                pr3[r] += u * cwn;
            }
        }
#pragma unroll
        for (int r = 0; r < 4; ++r) {
            float p = pr3[r];
            p += __shfl_xor(p, 1);
            p += __shfl_xor(p, 2);
            p += __shfl_xor(p, 4);
            p += __shfl_xor(p, 8);
            pr3[r] = p;
        }
        int i = 0;
        while (i < 16) {
            int node = sRow[grp * 16 + i];
            int j = i + 1;
            while (j < 16 && sRow[grp * 16 + j] == node) ++j;
            float s = 0.f;
            if (ln < 3) {
#pragma unroll
                for (int r = 0; r < 4; ++r) {
                    int el = quad * 4 + r;
                    int m = grp * 16 + el;
                    bool ok = (el >= i) && (el < j) && (e0 + m < E);
                    s += ok ? sCD[m][ln] * pr3[r] : 0.f;
                }
            }
            s += __shfl_xor(s, 16);
            s += __shfl_xor(s, 32);
            if (quad == 0 && ln < 3)
                atomicAdd(&aggx[node * 3 + ln], s);
            i = j;
        }
    }
}

// MFMA node kernel: 16 nodes/block, 4 waves; wave wv owns output channels
// [wv*32, wv*32+32). Two shared split-bf16 [16][128] tiles (h/act in t0,
// agg/h_new in t1). Fuses vel+x update (zeroing aggx), aggh zeroing, node MLP,
// and next-layer Hrow/Hcol (hpre, eb1 folded).
__global__ __launch_bounds__(256, 4) void k_node_mfma(
    float* __restrict__ h, float* __restrict__ aggh,
    float* __restrict__ aggx, const int* __restrict__ cnti,
    float* __restrict__ x, float* __restrict__ vel,
    const unsigned short* __restrict__ v1p, const float* __restrict__ vb1,
    const float* __restrict__ vw2, const float* __restrict__ vb2,
    const unsigned short* __restrict__ n1ap, const unsigned short* __restrict__ n1bp,
    const float* __restrict__ nb1,
    const unsigned short* __restrict__ n2p, const float* __restrict__ nb2,
    const unsigned short* __restrict__ hrp, const unsigned short* __restrict__ hcp,
    const float* __restrict__ eb1n,
    float* __restrict__ Hrow, float* __restrict__ Hcol, int N, int last)
{
    __shared__ __align__(16) unsigned short t0Hi[16][136], t0Lo[16][136];
    __shared__ __align__(16) unsigned short t1Hi[16][136], t1Lo[16][136];
    __shared__ float sVel[4][16];

    const int t = threadIdx.x;
    const int wv = t >> 6, lane = t & 63;
    const int quad = lane >> 4, ln = lane & 15;
    const int n0 = blockIdx.x * 16;

    // ---- build h-tile (t0) and agg-tile (t1); zero aggh after read
    {
        int node = t >> 4, kb = (t & 15) * 8;
        int n = n0 + node;
        int nc = n < N ? n : N - 1;
        f32x4 a0 = *(const f32x4*)&h[(size_t)nc * HID + kb];
        f32x4 a1 = *(const f32x4*)&h[(size_t)nc * HID + kb + 4];
        f32x4 g0 = *(const f32x4*)&aggh[(size_t)nc * HID + kb];
        f32x4 g1 = *(const f32x4*)&aggh[(size_t)nc * HID + kb + 4];
        if (n < N) {
            *(f32x4*)&aggh[(size_t)n * HID + kb]     = (f32x4){0.f, 0.f, 0.f, 0.f};
            *(f32x4*)&aggh[(size_t)n * HID + kb + 4] = (f32x4){0.f, 0.f, 0.f, 0.f};
        }
        bf16x8 hh, hl, gh, gl;
#pragma unroll
        for (int j = 0; j < 4; ++j) {
            unsigned short u0 = bf16hi(a0[j]);
            unsigned short u1 = bf16hi(a1[j]);
            hh[j] = (short)u0; hh[j + 4] = (short)u1;
            hl[j] = (short)bf16hi(a0[j] - bf16tof(u0));
            hl[j + 4] = (short)bf16hi(a1[j] - bf16tof(u1));
            unsigned short v0 = bf16hi(g0[j]);
            unsigned short v1 = bf16hi(g1[j]);
            gh[j] = (short)v0; gh[j + 4] = (short)v1;
            gl[j] = (short)bf16hi(g0[j] - bf16tof(v0));
            gl[j + 4] = (short)bf16hi(g1[j] - bf16tof(v1));
        }
        *(bf16x8*)&t0Hi[node][kb] = hh;
        *(bf16x8*)&t0Lo[node][kb] = hl;
        *(bf16x8*)&t1Hi[node][kb] = gh;
        *(bf16x8*)&t1Lo[node][kb] = gl;
    }
    __syncthreads();   // tiles ready

    // ---- A-fragments from h-tile
    bf16x8 ahi[4], alo[4];
#pragma unroll
    for (int kc = 0; kc < 4; ++kc) {
        ahi[kc] = *(const bf16x8*)&t0Hi[ln][kc * 32 + quad * 8];
        alo[kc] = *(const bf16x8*)&t0Lo[ln][kc * 32 + quad * 8];
    }

    // ---- vel GEMM (this wave's 32 channels)
    f32x4 av[2];
    av[0] = (f32x4){0.f, 0.f, 0.f, 0.f};
    av[1] = (f32x4){0.f, 0.f, 0.f, 0.f};
#pragma unroll
    for (int t8g = 0; t8g < 2; ++t8g) {
        const unsigned short* bg = v1p + quad * 2048 + ln * 8 + (wv * 2 + t8g) * 128;
#pragma unroll
        for (int kc = 0; kc < 4; ++kc) {
            bf16x8 bhi = *(const bf16x8*)(bg + kc * 8192);
            bf16x8 blo = *(const bf16x8*)(bg + kc * 8192 + 1024);
            av[t8g] = __builtin_amdgcn_mfma_f32_16x16x32_bf16(ahi[kc], bhi, av[t8g], 0, 0, 0);
            av[t8g] = __builtin_amdgcn_mfma_f32_16x16x32_bf16(alo[kc], bhi, av[t8g], 0, 0, 0);
            av[t8g] = __builtin_amdgcn_mfma_f32_16x16x32_bf16(ahi[kc], blo, av[t8g], 0, 0, 0);
        }
    }
    {
        float pv[4] = {0.f, 0.f, 0.f, 0.f};
#pragma unroll
        for (int t8g = 0; t8g < 2; ++t8g) {
            int ch = wv * 32 + t8g * 16 + ln;
            float b1 = vb1[ch], w2 = vw2[ch];
#pragma unroll
            for (int r = 0; r < 4; ++r)
                pv[r] += silu_f(av[t8g][r] + b1) * w2;
        }
#pragma unroll
        for (int r = 0; r < 4; ++r) {
            float p = pv[r];
            p += __shfl_xor(p, 1);
            p += __shfl_xor(p, 2);
            p += __shfl_xor(p, 4);
            p += __shfl_xor(p, 8);
            pv[r] = p;
        }
        if (ln == 0) {
#pragma unroll
            for (int r = 0; r < 4; ++r) sVel[wv][quad * 4 + r] = pv[r];
        }
    }

    // ---- n1: A=h (t0 frags) x n1ap, then A=agg (t1 frags) x n1bp
    f32x4 n1acc[2];
    n1acc[0] = (f32x4){0.f, 0.f, 0.f, 0.f};
    n1acc[1] = (f32x4){0.f, 0.f, 0.f, 0.f};
#pragma unroll
    for (int t8g = 0; t8g < 2; ++t8g) {
        const unsigned short* bg = n1ap + quad * 2048 + ln * 8 + (wv * 2 + t8g) * 128;
#pragma unroll
        for (int kc = 0; kc < 4; ++kc) {
            bf16x8 bhi = *(const bf16x8*)(bg + kc * 8192);
            bf16x8 blo = *(const bf16x8*)(bg + kc * 8192 + 1024);
            n1acc[t8g] = __builtin_amdgcn_mfma_f32_16x16x32_bf16(ahi[kc], bhi, n1acc[t8g], 0, 0, 0);
            n1acc[t8g] = __builtin_amdgcn_mfma_f32_16x16x32_bf16(alo[kc], bhi, n1acc[t8g], 0, 0, 0);
            n1acc[t8g] = __builtin_amdgcn_mfma_f32_16x16x32_bf16(ahi[kc], blo, n1acc[t8g], 0, 0, 0);
        }
    }
#pragma unroll
    for (int kc = 0; kc < 4; ++kc) {
        ahi[kc] = *(const bf16x8*)&t1Hi[ln][kc * 32 + quad * 8];
        alo[kc] = *(const bf16x8*)&t1Lo[ln][kc * 32 + quad * 8];
    }
#pragma unroll
    for (int t8g = 0; t8g < 2; ++t8g) {
        const unsigned short* bg = n1bp + quad * 2048 + ln * 8 + (wv * 2 + t8g) * 128;
#pragma unroll
        for (int kc = 0; kc < 4; ++kc) {
            bf16x8 bhi = *(const bf16x8*)(bg + kc * 8192);
            bf16x8 blo = *(const bf16x8*)(bg + kc * 8192 + 1024);
            n1acc[t8g] = __builtin_amdgcn_mfma_f32_16x16x32_bf16(ahi[kc], bhi, n1acc[t8g], 0, 0, 0);
            n1acc[t8g] = __builtin_amdgcn_mfma_f32_16x16x32_bf16(alo[kc], bhi, n1acc[t8g], 0, 0, 0);
            n1acc[t8g] = __builtin_amdgcn_mfma_f32_16x16x32_bf16(ahi[kc], blo, n1acc[t8g], 0, 0, 0);
        }
    }
    __syncthreads();   // sVel ready; all t0/t1 fragment reads done

    // ---- vel/x update (lanes 0..15 of wave 0); zero aggx
    if (t < 16) {
        int n = n0 + t;
        if (n < N) {
            float vs = sVel[0][t] + sVel[1][t] + sVel[2][t] + sVel[3][t] + vb2[0];
            float cc = fmaxf((float)cnti[n], 1.0f);
#pragma unroll
            for (int d = 0; d < 3; ++d) {
                float vn = vs * vel[n * 3 + d];
                float xn = x[n * 3 + d] + aggx[n * 3 + d] / cc + vn;
                vel[n * 3 + d] = vn;
                x[n * 3 + d] = xn;
                aggx[n * 3 + d] = 0.f;
            }
        }
    }

    // ---- act = silu(n1 + nb1); write split into t0 (overwrites h-tile)
#pragma unroll
    for (int t8g = 0; t8g < 2; ++t8g) {
        int ch = wv * 32 + t8g * 16 + ln;
        float bb = nb1[ch];
#pragma unroll
        for (int r = 0; r < 4; ++r) {
            float v = silu_f(n1acc[t8g][r] + bb);
            unsigned short hi = bf16hi(v);
            t0Hi[quad * 4 + r][ch] = hi;
            t0Lo[quad * 4 + r][ch] = bf16hi(v - bf16tof(hi));
        }
    }
    __syncthreads();   // act tile complete

    // ---- n2: h_new = act @ nw2 + nb2; store h; build h_new tile in t1
#pragma unroll
    for (int kc = 0; kc < 4; ++kc) {
        ahi[kc] = *(const bf16x8*)&t0Hi[ln][kc * 32 + quad * 8];
        alo[kc] = *(const bf16x8*)&t0Lo[ln][kc * 32 + quad * 8];
    }
    f32x4 n2acc[2];
    n2acc[0] = (f32x4){0.f, 0.f, 0.f, 0.f};
    n2acc[1] = (f32x4){0.f, 0.f, 0.f, 0.f};
#pragma unroll
    for (int t8g = 0; t8g < 2; ++t8g) {
        const unsigned short* bg = n2p + quad * 2048 + ln * 8 + (wv * 2 + t8g) * 128;
#pragma unroll
        for (int kc = 0; kc < 4; ++kc) {
            bf16x8 bhi = *(const bf16x8*)(bg + kc * 8192);
            bf16x8 blo = *(const bf16x8*)(bg + kc * 8192 + 1024);
            n2acc[t8g] = __builtin_amdgcn_mfma_f32_16x16x32_bf16(ahi[kc], bhi, n2acc[t8g], 0, 0, 0);
            n2acc[t8g] = __builtin_amdgcn_mfma_f32_16x16x32_bf16(alo[kc], bhi, n2acc[t8g], 0, 0, 0);
            n2acc[t8g] = __builtin_amdgcn_mfma_f32_16x16x32_bf16(ahi[kc], blo, n2acc[t8g], 0, 0, 0);
        }
    }
#pragma unroll
    for (int t8g = 0; t8g < 2; ++t8g) {
        int ch = wv * 32 + t8g * 16 + ln;
        float bb = nb2[ch];
#pragma unroll
        for (int r = 0; r < 4; ++r) {
            int node = quad * 4 + r;
            int n = n0 + node;
            float v = n2acc[t8g][r] + bb;
            unsigned short hi = bf16hi(v);
            t1Hi[node][ch] = hi;
            t1Lo[node][ch] = bf16hi(v - bf16tof(hi));
            if (n < N) h[(size_t)n * HID + ch] = v;
        }
    }
    if (last) return;
    __syncthreads();   // h_new tile complete

    // ---- fused hpre: [Hrow|Hcol] = h_new @ ew1n (K=128, N=256); eb1n into Hrow
#pragma unroll
    for (int kc = 0; kc < 4; ++kc) {
        ahi[kc] = *(const bf16x8*)&t1Hi[ln][kc * 32 + quad * 8];
        alo[kc] = *(const bf16x8*)&t1Lo[ln][kc * 32 + quad * 8];
    }
    const unsigned short* mat = (wv < 2) ? hrp : hcp;
    float* outg = (wv < 2) ? Hrow : Hcol;
    const bool isrow = (wv < 2);
    const int half = wv & 1;
    f32x4 hacc[4];
#pragma unroll
    for (int i = 0; i < 4; ++i) hacc[i] = (f32x4){0.f, 0.f, 0.f, 0.f};
#pragma unroll
    for (int t8g = 0; t8g < 4; ++t8g) {
        const unsigned short* bg = mat + quad * 2048 + ln * 8 + (half * 4 + t8g) * 128;
#pragma unroll
        for (int kc = 0; kc < 4; ++kc) {
            bf16x8 bhi = *(const bf16x8*)(bg + kc * 8192);
            bf16x8 blo = *(const bf16x8*)(bg + kc * 8192 + 1024);
            hacc[t8g] = __builtin_amdgcn_mfma_f32_16x16x32_bf16(ahi[kc], bhi, hacc[t8g], 0, 0, 0);
            hacc[t8g] = __builtin_amdgcn_mfma_f32_16x16x32_bf16(alo[kc], bhi, hacc[t8g], 0, 0, 0);
            hacc[t8g] = __builtin_amdgcn_mfma_f32_16x16x32_bf16(ahi[kc], blo, hacc[t8g], 0, 0, 0);
        }
    }
#pragma unroll
    for (int t8g = 0; t8g < 4; ++t8g) {
        int ch = half * 64 + t8g * 16 + ln;
        float bb = isrow ? eb1n[ch] : 0.f;
#pragma unroll
        for (int r = 0; r < 4; ++r) {
            int n = n0 + quad * 4 + r;
            if (n < N) outg[(size_t)n * HID + ch] = hacc[t8g][r] + bb;
        }
    }
}

__global__ void k_proj(const float* __restrict__ h, const float* __restrict__ pw,
                       const float* __restrict__ pb, float* __restrict__ out, int N) {
    int idx = blockIdx.x * 256 + threadIdx.x;
    if (idx >= N * 3) return;
    int n = idx / 3, p = idx % 3;
    float s = pb[p];
    const float* hr = &h[(size_t)n * HID];
#pragma unroll 8
    for (int k = 0; k < HID; ++k) s += hr[k] * pw[k * 3 + p];
    out[idx] = s;
}

extern "C" void kernel_launch(void* const* d_in, const int* in_sizes, int n_in,
                              void* d_out, int out_size, void* d_ws, size_t ws_size,
                              hipStream_t stream)
{
    const float* h_in  = (const float*)d_in[0];
    const float* x_in  = (const float*)d_in[1];
    const float* v_in  = (const float*)d_in[2];
    const float* eattr = (const float*)d_in[3];
    const int*   edges = (const int*)d_in[4];
    const float* emb_w = (const float*)d_in[5];
    const float* emb_b = (const float*)d_in[6];
    const float* ew1   = (const float*)d_in[7];
    const float* eb1   = (const float*)d_in[8];
    const float* ew2   = (const float*)d_in[9];
    const float* eb2   = (const float*)d_in[10];
    const float* aw    = (const float*)d_in[11];
    const float* ab    = (const float*)d_in[12];
    const float* nw1   = (const float*)d_in[13];
    const float* nb1   = (const float*)d_in[14];
    const float* nw2   = (const float*)d_in[15];
    const float* nb2   = (const float*)d_in[16];
    const float* cw1   = (const float*)d_in[17];
    const float* cb1   = (const float*)d_in[18];
    const float* cw2   = (const float*)d_in[19];
    const float* vw1   = (const float*)d_in[20];
    const float* vb1   = (const float*)d_in[21];
    const float* vw2   = (const float*)d_in[22];
    const float* vb2   = (const float*)d_in[23];
    const float* pw    = (const float*)d_in[24];
    const float* pb    = (const float*)d_in[25];

    const int N = in_sizes[0] / 6;
    const int E = in_sizes[4] / 2;
    const int* rows = edges;
    const int* cols = edges + E;

    float* ws   = (float*)d_ws;
    float* hbuf = ws;  ws += (size_t)N * HID;
    float* aggh = ws;  ws += (size_t)N * HID;
    float* aggx = ws;  ws += (size_t)N * 3;
    float* xb   = ws;  ws += (size_t)N * 3;
    float* vb   = ws;  ws += (size_t)N * 3;
    float* sea  = ws;  ws += (size_t)E * 2;
    float* Hrow = ws;  ws += (size_t)N * HID;
    float* Hcol = ws;  ws += (size_t)N * HID;
    int* wi = (int*)ws;
    int* cnti = wi;  wi += N;
    int* basei = wi; wi += N;
    int* fill = wi;  wi += N;
    int* srow = wi;  wi += E;
    int* scol = wi;  wi += E;
    unsigned short* us = (unsigned short*)wi;
    unsigned short* w2p  = us;  us += 4 * 32768;
    unsigned short* c1p  = us;  us += 4 * 32768;
    unsigned short* v1p  = us;  us += 4 * 32768;
    unsigned short* n1ap = us;  us += 4 * 32768;
    unsigned short* n1bp = us;  us += 4 * 32768;
    unsigned short* n2p  = us;  us += 4 * 32768;
    unsigned short* hrp  = us;  us += 4 * 32768;
    unsigned short* hcp  = us;  us += 4 * 32768;
    float* outp = (float*)d_out;

    hipMemcpyAsync(xb, x_in, (size_t)N * 3 * sizeof(float), hipMemcpyDeviceToDevice, stream);
    hipMemcpyAsync(vb, v_in, (size_t)N * 3 * sizeof(float), hipMemcpyDeviceToDevice, stream);
    hipMemsetAsync(cnti, 0, 2 * N * sizeof(int), stream);  // cnti+basei; fill separate
    hipMemsetAsync(fill, 0, N * sizeof(int), stream);
    hipMemsetAsync(aggh, 0, (size_t)N * HID * sizeof(float), stream);  // layer 0 only;
    hipMemsetAsync(aggx, 0, (size_t)N * 3 * sizeof(float), stream);    // k_node re-zeroes
    k_cnt<<<(E + 255) / 256, 256, 0, stream>>>(rows, cnti, E);
    k_scan<<<1, 256, 0, stream>>>(cnti, basei, N);
    k_scatter<<<(E + 255) / 256, 256, 0, stream>>>(rows, cols, eattr, basei, fill,
                                                   srow, scol, sea, E);
    k_pack_w<<<(4 * 32768 + 255) / 256, 256, 0, stream>>>(ew2, cw1, w2p, c1p);
    k_pack_node<<<(4 * 6 * 16384 + 255) / 256, 256, 0, stream>>>(
        vw1, nw1, nw2, ew1, v1p, n1ap, n1bp, n2p, hrp, hcp);
    k_embed<<<(N * HID + 255) / 256, 256, 0, stream>>>(h_in, emb_w, emb_b, hbuf, N);
    k_hpre<<<(N + 63) / 64, 256, 0, stream>>>(hbuf, ew1, eb1, Hrow, Hcol, N);

    for (int l = 0; l < 4; ++l) {
        k_edge_mfma<<<(E + 31) / 32, 256, 0, stream>>>(
            Hrow, Hcol, xb, srow, scol, sea,
            ew1 + (size_t)l * 33152 + 256 * HID,
            w2p + (size_t)l * 32768, eb2 + l * HID,
            aw + l * HID, ab + l,
            c1p + (size_t)l * 32768, cb1 + l * HID, cw2 + l * HID,
            aggh, aggx, E);
        int nl = l + 1;
        k_node_mfma<<<(N + 15) / 16, 256, 0, stream>>>(
            hbuf, aggh, aggx, cnti, xb, vb,
            v1p + (size_t)l * 32768, vb1 + l * HID, vw2 + l * HID, vb2 + l,
            n1ap + (size_t)l * 32768, n1bp + (size_t)l * 32768, nb1 + l * HID,
            n2p + (size_t)l * 32768, nb2 + l * HID,
            hrp + (size_t)(l < 3 ? nl : 0) * 32768,
            hcp + (size_t)(l < 3 ? nl : 0) * 32768,
            eb1 + (size_t)(l < 3 ? nl : 0) * HID,
            Hrow, Hcol, N, (l == 3) ? 1 : 0);
    }
    k_proj<<<(N * 3 + 255) / 256, 256, 0, stream>>>(hbuf, pw, pb, outp, N);
    hipMemcpyAsync(outp + (size_t)N * 3, xb, (size_t)N * 3 * sizeof(float), hipMemcpyDeviceToDevice, stream);
    hipMemcpyAsync(outp + (size_t)N * 6, vb, (size_t)N * 3 * sizeof(float), hipMemcpyDeviceToDevice, stream);
}

// Round 14
// 865.981 us; speedup vs baseline: 1.4903x; 1.0158x over previous
//
#include <hip/hip_runtime.h>
#include <math.h>

#define HID 128

typedef __attribute__((ext_vector_type(8))) short bf16x8;
typedef __attribute__((ext_vector_type(4))) float f32x4;

__device__ __forceinline__ float silu_f(float v) {
    return v * __builtin_amdgcn_rcpf(1.0f + __expf(-v));
}
__device__ __forceinline__ float sigmoid_f(float v) {
    return __builtin_amdgcn_rcpf(1.0f + __expf(-v));
}
__device__ __forceinline__ unsigned short bf16hi(float f) {
    return (unsigned short)(__float_as_uint(f) >> 16);
}
__device__ __forceinline__ float bf16tof(unsigned short u) {
    return __uint_as_float(((unsigned int)u) << 16);
}

// ---------- CSR / sort-by-row (rows static across layers; built once per call) ----------
__global__ void k_cnt(const int* __restrict__ rows, int* __restrict__ cnti, int E) {
    int i = blockIdx.x * 256 + threadIdx.x;
    if (i < E) atomicAdd(&cnti[rows[i]], 1);
}

// single-block exclusive scan over N counts -> base
__global__ void k_scan(const int* __restrict__ cnti, int* __restrict__ base, int N) {
    __shared__ int part[256];
    int t = threadIdx.x;
    int chunk = (N + 255) / 256;
    int lo = t * chunk, hi = lo + chunk < N ? lo + chunk : N;
    int s = 0;
    for (int i = lo; i < hi; ++i) s += cnti[i];
    part[t] = s;
    __syncthreads();
    for (int off = 1; off < 256; off <<= 1) {
        int v = (t >= off) ? part[t - off] : 0;
        __syncthreads();
        part[t] += v;
        __syncthreads();
    }
    int run = (t == 0) ? 0 : part[t - 1];
    for (int i = lo; i < hi; ++i) { base[i] = run; run += cnti[i]; }
}

__global__ void k_scatter(const int* __restrict__ rows, const int* __restrict__ cols,
                          const float* __restrict__ eattr,
                          const int* __restrict__ base, int* __restrict__ fill,
                          int* __restrict__ srow, int* __restrict__ scol,
                          float* __restrict__ sea, int E) {
    int e = blockIdx.x * 256 + threadIdx.x;
    if (e >= E) return;
    int r = rows[e];
    int pos = base[r] + atomicAdd(&fill[r], 1);
    srow[pos] = r;
    scol[pos] = cols[e];
    sea[pos * 2 + 0] = eattr[(size_t)e * 2 + 0];
    sea[pos * 2 + 1] = eattr[(size_t)e * 2 + 1];
}

// pack weights for MFMA (hi/lo split): s-block = [hi 1024 | lo 1024], entry n*8 + (k&7)
__global__ void k_pack_w(const float* __restrict__ ew2, const float* __restrict__ cw1,
                         unsigned short* __restrict__ w2p, unsigned short* __restrict__ c1p) {
    int idx = blockIdx.x * 256 + threadIdx.x;
    if (idx >= 4 * 32768) return;
    int l = idx >> 15, r = idx & 32767;
    const float* src;
    unsigned short* dst;
    int k, n;
    if (r < 16384) {
        k = r >> 7; n = r & 127;
        src = ew2 + (size_t)l * 16384 + k * 128 + n;
        dst = w2p + (size_t)l * 32768;
    } else {
        int rr = r - 16384; k = rr >> 7; n = rr & 127;
        src = cw1 + (size_t)l * 16384 + k * 128 + n;
        dst = c1p + (size_t)l * 32768;
    }
    float f = *src;
    unsigned short hi = bf16hi(f);
    float rem = f - bf16tof(hi);
    int s = k >> 3;
    int b = s * 2048 + n * 8 + (k & 7);
    dst[b] = hi;
    dst[b + 1024] = bf16hi(rem);
}

// pack node-phase weights: vw1 / nw1(two halves) / nw2 / ew1 rows 0:128, 128:256
__global__ void k_pack_node(const float* __restrict__ vw1, const float* __restrict__ nw1,
                            const float* __restrict__ nw2, const float* __restrict__ ew1,
                            unsigned short* __restrict__ v1p, unsigned short* __restrict__ n1ap,
                            unsigned short* __restrict__ n1bp, unsigned short* __restrict__ n2p,
                            unsigned short* __restrict__ hrp, unsigned short* __restrict__ hcp) {
    int idx = blockIdx.x * 256 + threadIdx.x;
    if (idx >= 4 * 6 * 16384) return;
    int l = idx / (6 * 16384);
    int r = idx % (6 * 16384);
    int m = r / 16384;
    int e = r % 16384;
    int k = e >> 7, n = e & 127;
    const float* src;
    unsigned short* dst;
    switch (m) {
        case 0: src = vw1 + (size_t)l * 16384 + k * 128 + n;            dst = v1p  + (size_t)l * 32768; break;
        case 1: src = nw1 + (size_t)l * 32768 + k * 128 + n;            dst = n1ap + (size_t)l * 32768; break;
        case 2: src = nw1 + (size_t)l * 32768 + (128 + k) * 128 + n;    dst = n1bp + (size_t)l * 32768; break;
        case 3: src = nw2 + (size_t)l * 16384 + k * 128 + n;            dst = n2p  + (size_t)l * 32768; break;
        case 4: src = ew1 + (size_t)l * 33152 + k * 128 + n;            dst = hrp  + (size_t)l * 32768; break;
        default: src = ew1 + (size_t)l * 33152 + (128 + k) * 128 + n;   dst = hcp  + (size_t)l * 32768; break;
    }
    float f = *src;
    unsigned short hi = bf16hi(f);
    float rem = f - bf16tof(hi);
    int s = k >> 3;
    int b = s * 2048 + n * 8 + (k & 7);
    dst[b] = hi;
    dst[b + 1024] = bf16hi(rem);
}

// fused embedding + layer-0 hpre: h = hin@emb_w + emb_b (written to hbuf),
// then Hrow = h @ ew1[0:128] + eb1, Hcol = h @ ew1[128:256]  (fp32, exact)
__global__ __launch_bounds__(256, 2) void k_embed_hpre(
    const float* __restrict__ hin, const float* __restrict__ emb_w,
    const float* __restrict__ emb_b,
    const float* __restrict__ w, const float* __restrict__ eb1,
    float* __restrict__ hbuf,
    float* __restrict__ Hrow, float* __restrict__ Hcol, int N)
{
    __shared__ __align__(16) float BH[64][132];
    const int t = threadIdx.x;
    const int tx = t & 15, ty = t >> 4;
    const int n0 = blockIdx.x * 64;

    for (int idx = t; idx < 64 * 32; idx += 256) {
        int r = idx >> 5, c4 = idx & 31;
        int n = n0 + r;
        float4 v0 = make_float4(0.f, 0.f, 0.f, 0.f);
        if (n < N) {
            const float* hr = &hin[n * 6];
            float h0 = hr[0], h1 = hr[1], h2 = hr[2];
            float h3 = hr[3], h4 = hr[4], h5 = hr[5];
            float vv[4];
#pragma unroll
            for (int jj = 0; jj < 4; ++jj) {
                int j = c4 * 4 + jj;
                float s = emb_b[j];
                s += h0 * emb_w[0 * HID + j];
                s += h1 * emb_w[1 * HID + j];
                s += h2 * emb_w[2 * HID + j];
                s += h3 * emb_w[3 * HID + j];
                s += h4 * emb_w[4 * HID + j];
                s += h5 * emb_w[5 * HID + j];
                vv[jj] = s;
            }
            v0 = make_float4(vv[0], vv[1], vv[2], vv[3]);
            *(float4*)&hbuf[(size_t)n * HID + c4 * 4] = v0;
        }
        *(float4*)&BH[r][c4 * 4] = v0;
    }
    __syncthreads();

    float ar[4][8], ac[4][8];
#pragma unroll
    for (int i = 0; i < 4; ++i)
#pragma unroll
        for (int j = 0; j < 8; ++j) { ar[i][j] = 0.f; ac[i][j] = 0.f; }

    const float* wr = &w[tx * 8];
    const float* wc = &w[128 * HID + tx * 8];
#pragma unroll 4
    for (int k = 0; k < HID; ++k) {
        float4 r0 = *(const float4*)&wr[k * HID];
        float4 r1 = *(const float4*)&wr[k * HID + 4];
        float4 c0 = *(const float4*)&wc[k * HID];
        float4 c1 = *(const float4*)&wc[k * HID + 4];
        float rv[8] = {r0.x, r0.y, r0.z, r0.w, r1.x, r1.y, r1.z, r1.w};
        float cv[8] = {c0.x, c0.y, c0.z, c0.w, c1.x, c1.y, c1.z, c1.w};
        float av[4];
#pragma unroll
        for (int i = 0; i < 4; ++i) av[i] = BH[ty * 4 + i][k];
#pragma unroll
        for (int i = 0; i < 4; ++i)
#pragma unroll
            for (int j = 0; j < 8; ++j) {
                ar[i][j] += av[i] * rv[j];
                ac[i][j] += av[i] * cv[j];
            }
    }
#pragma unroll
    for (int i = 0; i < 4; ++i) {
        int n = n0 + ty * 4 + i;
        if (n < N) {
#pragma unroll
            for (int j = 0; j < 8; ++j) {
                Hrow[(size_t)n * HID + tx * 8 + j] = ar[i][j] + eb1[tx * 8 + j];
                Hcol[(size_t)n * HID + tx * 8 + j] = ac[i][j];
            }
        }
    }
}

// MFMA edge kernel over SORTED edges: 32 edges/block, 4 waves = 2 groups x 2
// channel-half waves. GEMM2/GEMM3 use kc-outer fragment streaming (no spill
// at 8 blocks/CU). s_setprio(1) around MFMA clusters (phase-diverse blocks).
__global__ __launch_bounds__(256, 8) void k_edge_mfma(
    const float* __restrict__ Hrow, const float* __restrict__ Hcol,
    const float* __restrict__ x,
    const int* __restrict__ srow, const int* __restrict__ scol,
    const float* __restrict__ sea,
    const float* __restrict__ ew1_tail,
    const unsigned short* __restrict__ w2p, const float* __restrict__ eb2,
    const float* __restrict__ aw, const float* __restrict__ ab,
    const unsigned short* __restrict__ c1p, const float* __restrict__ cb1,
    const float* __restrict__ cw2,
    float* __restrict__ aggh, float* __restrict__ aggx, int E)
{
    __shared__ __align__(16) unsigned short tHi[2][16][136];
    __shared__ __align__(16) unsigned short tLo[2][16][136];
    __shared__ float sGate[2][2][16];
    __shared__ float sCD[32][4];
    __shared__ float sEA[32][2];
    __shared__ int sRow[32], sCol[32];

    const int t = threadIdx.x;
    const int wv = t >> 6, lane = t & 63;
    const int grp = wv >> 1, hf = wv & 1;
    const int quad = lane >> 4, ln = lane & 15;
    const int e0 = blockIdx.x * 32;

    if (lane < 16) {
        int eg = e0 + grp * 16 + lane;
        int ec = eg < E ? eg : E - 1;
        int r = srow[ec], c = scol[ec];
        sRow[grp * 16 + lane] = r; sCol[grp * 16 + lane] = c;
        float dx = x[r * 3 + 0] - x[c * 3 + 0];
        float dy = x[r * 3 + 1] - x[c * 3 + 1];
        float dz = x[r * 3 + 2] - x[c * 3 + 2];
        sCD[grp * 16 + lane][0] = dx;
        sCD[grp * 16 + lane][1] = dy;
        sCD[grp * 16 + lane][2] = dz;
        sCD[grp * 16 + lane][3] = dx * dx + dy * dy + dz * dz;
        sEA[grp * 16 + lane][0] = sea[(size_t)ec * 2 + 0];
        sEA[grp * 16 + lane][1] = sea[(size_t)ec * 2 + 1];
    }

    const int eM = grp * 16 + ln;
    const int rn = sRow[eM], cn = sCol[eM];
    const float rad = sCD[eM][3], ea0 = sEA[eM][0], ea1 = sEA[eM][1];

    // ---- phase 1: e_act (fused GEMM1) for this wave's channel half; edge = ln
#pragma unroll
    for (int kk = 0; kk < 2; ++kk) {
        const int kc = hf * 2 + kk;
        const int fb = kc * 32 + quad * 8;
        f32x4 a0 = *(const f32x4*)(Hrow + (size_t)rn * HID + fb);
        f32x4 a1 = *(const f32x4*)(Hrow + (size_t)rn * HID + fb + 4);
        f32x4 c0 = *(const f32x4*)(Hcol + (size_t)cn * HID + fb);
        f32x4 c1 = *(const f32x4*)(Hcol + (size_t)cn * HID + fb + 4);
        f32x4 w60 = *(const f32x4*)(ew1_tail + fb);
        f32x4 w61 = *(const f32x4*)(ew1_tail + fb + 4);
        f32x4 w70 = *(const f32x4*)(ew1_tail + 128 + fb);
        f32x4 w71 = *(const f32x4*)(ew1_tail + 128 + fb + 4);
        f32x4 w80 = *(const f32x4*)(ew1_tail + 256 + fb);
        f32x4 w81 = *(const f32x4*)(ew1_tail + 256 + fb + 4);
        bf16x8 ahi, alo;
#pragma unroll
        for (int j = 0; j < 4; ++j) {
            float s0 = a0[j] + c0[j] + rad * w60[j] + ea0 * w70[j] + ea1 * w80[j];
            float s1 = a1[j] + c1[j] + rad * w61[j] + ea0 * w71[j] + ea1 * w81[j];
            s0 = silu_f(s0);
            s1 = silu_f(s1);
            unsigned short h0 = bf16hi(s0), h1 = bf16hi(s1);
            ahi[j] = (short)h0;
            ahi[j + 4] = (short)h1;
            alo[j] = (short)bf16hi(s0 - bf16tof(h0));
            alo[j + 4] = (short)bf16hi(s1 - bf16tof(h1));
        }
        *(bf16x8*)&tHi[grp][ln][fb] = ahi;
        *(bf16x8*)&tLo[grp][ln][fb] = alo;
    }
    __syncthreads();   // barrier A: e_act tile complete

    // ---- GEMM2: kc-outer fragment streaming (one A-pair live at a time)
    f32x4 acc2[4];
#pragma unroll
    for (int i = 0; i < 4; ++i) acc2[i] = (f32x4){0.f, 0.f, 0.f, 0.f};
    __builtin_amdgcn_s_setprio(1);
#pragma unroll
    for (int kc = 0; kc < 4; ++kc) {
        bf16x8 fhi = *(const bf16x8*)&tHi[grp][ln][kc * 32 + quad * 8];
        bf16x8 flo = *(const bf16x8*)&tLo[grp][ln][kc * 32 + quad * 8];
        const unsigned short* bgk = w2p + kc * 8192 + quad * 2048 + ln * 8 + hf * 512;
#pragma unroll
        for (int t8l = 0; t8l < 4; ++t8l) {
            bf16x8 bhi = *(const bf16x8*)(bgk + t8l * 128);
            bf16x8 blo = *(const bf16x8*)(bgk + t8l * 128 + 1024);
            acc2[t8l] = __builtin_amdgcn_mfma_f32_16x16x32_bf16(fhi, bhi, acc2[t8l], 0, 0, 0);
            acc2[t8l] = __builtin_amdgcn_mfma_f32_16x16x32_bf16(flo, bhi, acc2[t8l], 0, 0, 0);
            acc2[t8l] = __builtin_amdgcn_mfma_f32_16x16x32_bf16(fhi, blo, acc2[t8l], 0, 0, 0);
        }
    }
    __builtin_amdgcn_s_setprio(0);

    // ---- silu + gate partial over this half's channels
    float pr[4] = {0.f, 0.f, 0.f, 0.f};
#pragma unroll
    for (int t8l = 0; t8l < 4; ++t8l) {
        int n = (hf * 4 + t8l) * 16 + ln;
        float bb = eb2[n], awn = aw[n];
#pragma unroll
        for (int r = 0; r < 4; ++r) {
            float v = silu_f(acc2[t8l][r] + bb);
            acc2[t8l][r] = v;
            pr[r] += v * awn;
        }
    }
#pragma unroll
    for (int r = 0; r < 4; ++r) {
        float p = pr[r];
        p += __shfl_xor(p, 1);
        p += __shfl_xor(p, 2);
        p += __shfl_xor(p, 4);
        p += __shfl_xor(p, 8);
        pr[r] = p;
    }
    if (ln == 0) {
#pragma unroll
        for (int r = 0; r < 4; ++r) sGate[grp][hf][quad * 4 + r] = pr[r];
    }
    __syncthreads();   // barrier B: gate partials ready; all e_act reads done

    float gate[4];
    {
        float ab0 = ab[0];
#pragma unroll
        for (int r = 0; r < 4; ++r)
            gate[r] = sigmoid_f(sGate[grp][0][quad * 4 + r] +
                                sGate[grp][1][quad * 4 + r] + ab0);
    }

    // ---- gate + write m (this half) into the tile (overwrites own e_act half)
#pragma unroll
    for (int t8l = 0; t8l < 4; ++t8l) {
        int n = (hf * 4 + t8l) * 16 + ln;
#pragma unroll
        for (int r = 0; r < 4; ++r) {
            float v = acc2[t8l][r] * gate[r];
            acc2[t8l][r] = v;                 // keep gated m (fp32) for agg_h
            unsigned short hi = bf16hi(v);
            float rem = v - bf16tof(hi);
            tHi[grp][quad * 4 + r][n] = hi;
            tLo[grp][quad * 4 + r][n] = bf16hi(rem);
        }
    }

    // ---- agg_h: run-segmented reduction (this half's channels, exact fp32)
    {
        int i = 0;
        while (i < 16) {
            int node = sRow[grp * 16 + i];
            int j = i + 1;
            while (j < 16 && sRow[grp * 16 + j] == node) ++j;
#pragma unroll
            for (int t8l = 0; t8l < 4; ++t8l) {
                float s = 0.f;
#pragma unroll
                for (int r = 0; r < 4; ++r) {
                    int el = quad * 4 + r;
                    bool ok = (el >= i) && (el < j) && (e0 + grp * 16 + el < E);
                    s += ok ? acc2[t8l][r] : 0.f;
                }
                s += __shfl_xor(s, 16);
                s += __shfl_xor(s, 32);
                if (quad == (t8l & 3))
                    atomicAdd(&aggh[(size_t)node * HID + (hf * 4 + t8l) * 16 + ln], s);
            }
            i = j;
        }
    }
    __syncthreads();   // barrier C: m tile complete

    // ---- GEMM3: kc-outer fragment streaming
    f32x4 acc3[4];
#pragma unroll
    for (int i = 0; i < 4; ++i) acc3[i] = (f32x4){0.f, 0.f, 0.f, 0.f};
    __builtin_amdgcn_s_setprio(1);
#pragma unroll
    for (int kc = 0; kc < 4; ++kc) {
        bf16x8 fhi = *(const bf16x8*)&tHi[grp][ln][kc * 32 + quad * 8];
        bf16x8 flo = *(const bf16x8*)&tLo[grp][ln][kc * 32 + quad * 8];
        const unsigned short* bgk = c1p + kc * 8192 + quad * 2048 + ln * 8 + hf * 512;
#pragma unroll
        for (int t8l = 0; t8l < 4; ++t8l) {
            bf16x8 bhi = *(const bf16x8*)(bgk + t8l * 128);
            bf16x8 blo = *(const bf16x8*)(bgk + t8l * 128 + 1024);
            acc3[t8l] = __builtin_amdgcn_mfma_f32_16x16x32_bf16(fhi, bhi, acc3[t8l], 0, 0, 0);
            acc3[t8l] = __builtin_amdgcn_mfma_f32_16x16x32_bf16(flo, bhi, acc3[t8l], 0, 0, 0);
            acc3[t8l] = __builtin_amdgcn_mfma_f32_16x16x32_bf16(fhi, blo, acc3[t8l], 0, 0, 0);
        }
    }
    __builtin_amdgcn_s_setprio(0);
    {
        float pr3[4] = {0.f, 0.f, 0.f, 0.f};
#pragma unroll
        for (int t8l = 0; t8l < 4; ++t8l) {
            int n = (hf * 4 + t8l) * 16 + ln;
            float bb = cb1[n], cwn = cw2[n];
#pragma unroll
            for (int r = 0; r < 4; ++r) {
                float u = silu_f(acc3[t8l][r] + bb);
                pr3[r] += u * cwn;
            }
        }
#pragma unroll
        for (int r = 0; r < 4; ++r) {
            float p = pr3[r];
            p += __shfl_xor(p, 1);
            p += __shfl_xor(p, 2);
            p += __shfl_xor(p, 4);
            p += __shfl_xor(p, 8);
            pr3[r] = p;
        }
        int i = 0;
        while (i < 16) {
            int node = sRow[grp * 16 + i];
            int j = i + 1;
            while (j < 16 && sRow[grp * 16 + j] == node) ++j;
            float s = 0.f;
            if (ln < 3) {
#pragma unroll
                for (int r = 0; r < 4; ++r) {
                    int el = quad * 4 + r;
                    int m = grp * 16 + el;
                    bool ok = (el >= i) && (el < j) && (e0 + m < E);
                    s += ok ? sCD[m][ln] * pr3[r] : 0.f;
                }
            }
            s += __shfl_xor(s, 16);
            s += __shfl_xor(s, 32);
            if (quad == 0 && ln < 3)
                atomicAdd(&aggx[node * 3 + ln], s);
            i = j;
        }
    }
}

// MFMA node kernel: 16 nodes/block, 4 waves; wave wv owns output channels
// [wv*32, wv*32+32). Fuses vel+x update (zeroing aggx), aggh zeroing, node MLP,
// next-layer Hrow/Hcol (hpre, eb1 folded), and (last layer) the h@proj output.
__global__ __launch_bounds__(256, 4) void k_node_mfma(
    float* __restrict__ h, float* __restrict__ aggh,
    float* __restrict__ aggx, const int* __restrict__ cnti,
    float* __restrict__ x, float* __restrict__ vel,
    const unsigned short* __restrict__ v1p, const float* __restrict__ vb1,
    const float* __restrict__ vw2, const float* __restrict__ vb2,
    const unsigned short* __restrict__ n1ap, const unsigned short* __restrict__ n1bp,
    const float* __restrict__ nb1,
    const unsigned short* __restrict__ n2p, const float* __restrict__ nb2,
    const unsigned short* __restrict__ hrp, const unsigned short* __restrict__ hcp,
    const float* __restrict__ eb1n,
    float* __restrict__ Hrow, float* __restrict__ Hcol,
    const float* __restrict__ pw, const float* __restrict__ pb,
    float* __restrict__ outp, int N, int last)
{
    __shared__ __align__(16) unsigned short t0Hi[16][136], t0Lo[16][136];
    __shared__ __align__(16) unsigned short t1Hi[16][136], t1Lo[16][136];
    __shared__ float sVel[4][16];
    __shared__ float sProj[4][16][3];

    const int t = threadIdx.x;
    const int wv = t >> 6, lane = t & 63;
    const int quad = lane >> 4, ln = lane & 15;
    const int n0 = blockIdx.x * 16;

    // ---- build h-tile (t0) and agg-tile (t1); zero aggh after read
    {
        int node = t >> 4, kb = (t & 15) * 8;
        int n = n0 + node;
        int nc = n < N ? n : N - 1;
        f32x4 a0 = *(const f32x4*)&h[(size_t)nc * HID + kb];
        f32x4 a1 = *(const f32x4*)&h[(size_t)nc * HID + kb + 4];
        f32x4 g0 = *(const f32x4*)&aggh[(size_t)nc * HID + kb];
        f32x4 g1 = *(const f32x4*)&aggh[(size_t)nc * HID + kb + 4];
        if (n < N) {
            *(f32x4*)&aggh[(size_t)n * HID + kb]     = (f32x4){0.f, 0.f, 0.f, 0.f};
            *(f32x4*)&aggh[(size_t)n * HID + kb + 4] = (f32x4){0.f, 0.f, 0.f, 0.f};
        }
        bf16x8 hh, hl, gh, gl;
#pragma unroll
        for (int j = 0; j < 4; ++j) {
            unsigned short u0 = bf16hi(a0[j]);
            unsigned short u1 = bf16hi(a1[j]);
            hh[j] = (short)u0; hh[j + 4] = (short)u1;
            hl[j] = (short)bf16hi(a0[j] - bf16tof(u0));
            hl[j + 4] = (short)bf16hi(a1[j] - bf16tof(u1));
            unsigned short v0 = bf16hi(g0[j]);
            unsigned short v1 = bf16hi(g1[j]);
            gh[j] = (short)v0; gh[j + 4] = (short)v1;
            gl[j] = (short)bf16hi(g0[j] - bf16tof(v0));
            gl[j + 4] = (short)bf16hi(g1[j] - bf16tof(v1));
        }
        *(bf16x8*)&t0Hi[node][kb] = hh;
        *(bf16x8*)&t0Lo[node][kb] = hl;
        *(bf16x8*)&t1Hi[node][kb] = gh;
        *(bf16x8*)&t1Lo[node][kb] = gl;
    }
    __syncthreads();   // tiles ready

    // ---- A-fragments from h-tile
    bf16x8 ahi[4], alo[4];
#pragma unroll
    for (int kc = 0; kc < 4; ++kc) {
        ahi[kc] = *(const bf16x8*)&t0Hi[ln][kc * 32 + quad * 8];
        alo[kc] = *(const bf16x8*)&t0Lo[ln][kc * 32 + quad * 8];
    }

    // ---- vel GEMM (this wave's 32 channels)
    f32x4 av[2];
    av[0] = (f32x4){0.f, 0.f, 0.f, 0.f};
    av[1] = (f32x4){0.f, 0.f, 0.f, 0.f};
#pragma unroll
    for (int t8g = 0; t8g < 2; ++t8g) {
        const unsigned short* bg = v1p + quad * 2048 + ln * 8 + (wv * 2 + t8g) * 128;
#pragma unroll
        for (int kc = 0; kc < 4; ++kc) {
            bf16x8 bhi = *(const bf16x8*)(bg + kc * 8192);
            bf16x8 blo = *(const bf16x8*)(bg + kc * 8192 + 1024);
            av[t8g] = __builtin_amdgcn_mfma_f32_16x16x32_bf16(ahi[kc], bhi, av[t8g], 0, 0, 0);
            av[t8g] = __builtin_amdgcn_mfma_f32_16x16x32_bf16(alo[kc], bhi, av[t8g], 0, 0, 0);
            av[t8g] = __builtin_amdgcn_mfma_f32_16x16x32_bf16(ahi[kc], blo, av[t8g], 0, 0, 0);
        }
    }
    {
        float pv[4] = {0.f, 0.f, 0.f, 0.f};
#pragma unroll
        for (int t8g = 0; t8g < 2; ++t8g) {
            int ch = wv * 32 + t8g * 16 + ln;
            float b1 = vb1[ch], w2 = vw2[ch];
#pragma unroll
            for (int r = 0; r < 4; ++r)
                pv[r] += silu_f(av[t8g][r] + b1) * w2;
        }
#pragma unroll
        for (int r = 0; r < 4; ++r) {
            float p = pv[r];
            p += __shfl_xor(p, 1);
            p += __shfl_xor(p, 2);
            p += __shfl_xor(p, 4);
            p += __shfl_xor(p, 8);
            pv[r] = p;
        }
        if (ln == 0) {
#pragma unroll
            for (int r = 0; r < 4; ++r) sVel[wv][quad * 4 + r] = pv[r];
        }
    }

    // ---- n1: A=h (t0 frags) x n1ap, then A=agg (t1 frags) x n1bp
    f32x4 n1acc[2];
    n1acc[0] = (f32x4){0.f, 0.f, 0.f, 0.f};
    n1acc[1] = (f32x4){0.f, 0.f, 0.f, 0.f};
#pragma unroll
    for (int t8g = 0; t8g < 2; ++t8g) {
        const unsigned short* bg = n1ap + quad * 2048 + ln * 8 + (wv * 2 + t8g) * 128;
#pragma unroll
        for (int kc = 0; kc < 4; ++kc) {
            bf16x8 bhi = *(const bf16x8*)(bg + kc * 8192);
            bf16x8 blo = *(const bf16x8*)(bg + kc * 8192 + 1024);
            n1acc[t8g] = __builtin_amdgcn_mfma_f32_16x16x32_bf16(ahi[kc], bhi, n1acc[t8g], 0, 0, 0);
            n1acc[t8g] = __builtin_amdgcn_mfma_f32_16x16x32_bf16(alo[kc], bhi, n1acc[t8g], 0, 0, 0);
            n1acc[t8g] = __builtin_amdgcn_mfma_f32_16x16x32_bf16(ahi[kc], blo, n1acc[t8g], 0, 0, 0);
        }
    }
#pragma unroll
    for (int kc = 0; kc < 4; ++kc) {
        ahi[kc] = *(const bf16x8*)&t1Hi[ln][kc * 32 + quad * 8];
        alo[kc] = *(const bf16x8*)&t1Lo[ln][kc * 32 + quad * 8];
    }
#pragma unroll
    for (int t8g = 0; t8g < 2; ++t8g) {
        const unsigned short* bg = n1bp + quad * 2048 + ln * 8 + (wv * 2 + t8g) * 128;
#pragma unroll
        for (int kc = 0; kc < 4; ++kc) {
            bf16x8 bhi = *(const bf16x8*)(bg + kc * 8192);
            bf16x8 blo = *(const bf16x8*)(bg + kc * 8192 + 1024);
            n1acc[t8g] = __builtin_amdgcn_mfma_f32_16x16x32_bf16(ahi[kc], bhi, n1acc[t8g], 0, 0, 0);
            n1acc[t8g] = __builtin_amdgcn_mfma_f32_16x16x32_bf16(alo[kc], bhi, n1acc[t8g], 0, 0, 0);
            n1acc[t8g] = __builtin_amdgcn_mfma_f32_16x16x32_bf16(ahi[kc], blo, n1acc[t8g], 0, 0, 0);
        }
    }
    __syncthreads();   // sVel ready; all t0/t1 fragment reads done

    // ---- vel/x update (lanes 0..15 of wave 0); zero aggx
    if (t < 16) {
        int n = n0 + t;
        if (n < N) {
            float vs = sVel[0][t] + sVel[1][t] + sVel[2][t] + sVel[3][t] + vb2[0];
            float cc = fmaxf((float)cnti[n], 1.0f);
#pragma unroll
            for (int d = 0; d < 3; ++d) {
                float vn = vs * vel[n * 3 + d];
                float xn = x[n * 3 + d] + aggx[n * 3 + d] / cc + vn;
                vel[n * 3 + d] = vn;
                x[n * 3 + d] = xn;
                aggx[n * 3 + d] = 0.f;
            }
        }
    }

    // ---- act = silu(n1 + nb1); write split into t0 (overwrites h-tile)
#pragma unroll
    for (int t8g = 0; t8g < 2; ++t8g) {
        int ch = wv * 32 + t8g * 16 + ln;
        float bb = nb1[ch];
#pragma unroll
        for (int r = 0; r < 4; ++r) {
            float v = silu_f(n1acc[t8g][r] + bb);
            unsigned short hi = bf16hi(v);
            t0Hi[quad * 4 + r][ch] = hi;
            t0Lo[quad * 4 + r][ch] = bf16hi(v - bf16tof(hi));
        }
    }
    __syncthreads();   // act tile complete

    // ---- n2: h_new = act @ nw2 + nb2; store h; build h_new tile in t1
#pragma unroll
    for (int kc = 0; kc < 4; ++kc) {
        ahi[kc] = *(const bf16x8*)&t0Hi[ln][kc * 32 + quad * 8];
        alo[kc] = *(const bf16x8*)&t0Lo[ln][kc * 32 + quad * 8];
    }
    f32x4 n2acc[2];
    n2acc[0] = (f32x4){0.f, 0.f, 0.f, 0.f};
    n2acc[1] = (f32x4){0.f, 0.f, 0.f, 0.f};
#pragma unroll
    for (int t8g = 0; t8g < 2; ++t8g) {
        const unsigned short* bg = n2p + quad * 2048 + ln * 8 + (wv * 2 + t8g) * 128;
#pragma unroll
        for (int kc = 0; kc < 4; ++kc) {
            bf16x8 bhi = *(const bf16x8*)(bg + kc * 8192);
            bf16x8 blo = *(const bf16x8*)(bg + kc * 8192 + 1024);
            n2acc[t8g] = __builtin_amdgcn_mfma_f32_16x16x32_bf16(ahi[kc], bhi, n2acc[t8g], 0, 0, 0);
            n2acc[t8g] = __builtin_amdgcn_mfma_f32_16x16x32_bf16(alo[kc], bhi, n2acc[t8g], 0, 0, 0);
            n2acc[t8g] = __builtin_amdgcn_mfma_f32_16x16x32_bf16(ahi[kc], blo, n2acc[t8g], 0, 0, 0);
        }
    }
    float hvv[2][4];
#pragma unroll
    for (int t8g = 0; t8g < 2; ++t8g) {
        int ch = wv * 32 + t8g * 16 + ln;
        float bb = nb2[ch];
#pragma unroll
        for (int r = 0; r < 4; ++r) {
            int node = quad * 4 + r;
            int n = n0 + node;
            float v = n2acc[t8g][r] + bb;
            hvv[t8g][r] = v;
            unsigned short hi = bf16hi(v);
            t1Hi[node][ch] = hi;
            t1Lo[node][ch] = bf16hi(v - bf16tof(hi));
            if (n < N) h[(size_t)n * HID + ch] = v;
        }
    }

    if (last) {
        // ---- fused projection: out[n, 0:3] = pb + h_new @ pw
        float prj[4][3];
#pragma unroll
        for (int r = 0; r < 4; ++r) { prj[r][0] = 0.f; prj[r][1] = 0.f; prj[r][2] = 0.f; }
#pragma unroll
        for (int t8g = 0; t8g < 2; ++t8g) {
            int ch = wv * 32 + t8g * 16 + ln;
            float w0 = pw[ch * 3 + 0], w1 = pw[ch * 3 + 1], w2 = pw[ch * 3 + 2];
#pragma unroll
            for (int r = 0; r < 4; ++r) {
                prj[r][0] += hvv[t8g][r] * w0;
                prj[r][1] += hvv[t8g][r] * w1;
                prj[r][2] += hvv[t8g][r] * w2;
            }
        }
#pragma unroll
        for (int r = 0; r < 4; ++r)
#pragma unroll
            for (int p = 0; p < 3; ++p) {
                float s = prj[r][p];
                s += __shfl_xor(s, 1);
                s += __shfl_xor(s, 2);
                s += __shfl_xor(s, 4);
                s += __shfl_xor(s, 8);
                prj[r][p] = s;
            }
        if (ln == 0) {
#pragma unroll
            for (int r = 0; r < 4; ++r)
#pragma unroll
                for (int p = 0; p < 3; ++p)
                    sProj[wv][quad * 4 + r][p] = prj[r][p];
        }
        __syncthreads();
        if (t < 48) {
            int node = t / 3, p = t % 3;
            int n = n0 + node;
            if (n < N)
                outp[(size_t)n * 3 + p] = pb[p] + sProj[0][node][p] + sProj[1][node][p]
                                        + sProj[2][node][p] + sProj[3][node][p];
        }
        return;
    }
    __syncthreads();   // h_new tile complete

    // ---- fused hpre: [Hrow|Hcol] = h_new @ ew1n (K=128, N=256); eb1n into Hrow
#pragma unroll
    for (int kc = 0; kc < 4; ++kc) {
        ahi[kc] = *(const bf16x8*)&t1Hi[ln][kc * 32 + quad * 8];
        alo[kc] = *(const bf16x8*)&t1Lo[ln][kc * 32 + quad * 8];
    }
    const unsigned short* mat = (wv < 2) ? hrp : hcp;
    float* outg = (wv < 2) ? Hrow : Hcol;
    const bool isrow = (wv < 2);
    const int half = wv & 1;
    f32x4 hacc[4];
#pragma unroll
    for (int i = 0; i < 4; ++i) hacc[i] = (f32x4){0.f, 0.f, 0.f, 0.f};
#pragma unroll
    for (int t8g = 0; t8g < 4; ++t8g) {
        const unsigned short* bg = mat + quad * 2048 + ln * 8 + (half * 4 + t8g) * 128;
#pragma unroll
        for (int kc = 0; kc < 4; ++kc) {
            bf16x8 bhi = *(const bf16x8*)(bg + kc * 8192);
            bf16x8 blo = *(const bf16x8*)(bg + kc * 8192 + 1024);
            hacc[t8g] = __builtin_amdgcn_mfma_f32_16x16x32_bf16(ahi[kc], bhi, hacc[t8g], 0, 0, 0);
            hacc[t8g] = __builtin_amdgcn_mfma_f32_16x16x32_bf16(alo[kc], bhi, hacc[t8g], 0, 0, 0);
            hacc[t8g] = __builtin_amdgcn_mfma_f32_16x16x32_bf16(ahi[kc], blo, hacc[t8g], 0, 0, 0);
        }
    }
#pragma unroll
    for (int t8g = 0; t8g < 4; ++t8g) {
        int ch = half * 64 + t8g * 16 + ln;
        float bb = isrow ? eb1n[ch] : 0.f;
#pragma unroll
        for (int r = 0; r < 4; ++r) {
            int n = n0 + quad * 4 + r;
            if (n < N) outg[(size_t)n * HID + ch] = hacc[t8g][r] + bb;
        }
    }
}

extern "C" void kernel_launch(void* const* d_in, const int* in_sizes, int n_in,
                              void* d_out, int out_size, void* d_ws, size_t ws_size,
                              hipStream_t stream)
{
    const float* h_in  = (const float*)d_in[0];
    const float* x_in  = (const float*)d_in[1];
    const float* v_in  = (const float*)d_in[2];
    const float* eattr = (const float*)d_in[3];
    const int*   edges = (const int*)d_in[4];
    const float* emb_w = (const float*)d_in[5];
    const float* emb_b = (const float*)d_in[6];
    const float* ew1   = (const float*)d_in[7];
    const float* eb1   = (const float*)d_in[8];
    const float* ew2   = (const float*)d_in[9];
    const float* eb2   = (const float*)d_in[10];
    const float* aw    = (const float*)d_in[11];
    const float* ab    = (const float*)d_in[12];
    const float* nw1   = (const float*)d_in[13];
    const float* nb1   = (const float*)d_in[14];
    const float* nw2   = (const float*)d_in[15];
    const float* nb2   = (const float*)d_in[16];
    const float* cw1   = (const float*)d_in[17];
    const float* cb1   = (const float*)d_in[18];
    const float* cw2   = (const float*)d_in[19];
    const float* vw1   = (const float*)d_in[20];
    const float* vb1   = (const float*)d_in[21];
    const float* vw2   = (const float*)d_in[22];
    const float* vb2   = (const float*)d_in[23];
    const float* pw    = (const float*)d_in[24];
    const float* pb    = (const float*)d_in[25];

    const int N = in_sizes[0] / 6;
    const int E = in_sizes[4] / 2;
    const int* rows = edges;
    const int* cols = edges + E;

    float* ws   = (float*)d_ws;
    float* hbuf = ws;  ws += (size_t)N * HID;
    float* aggh = ws;  ws += (size_t)N * HID;
    float* aggx = ws;  ws += (size_t)N * 3;
    float* xb   = ws;  ws += (size_t)N * 3;
    float* vb   = ws;  ws += (size_t)N * 3;
    float* sea  = ws;  ws += (size_t)E * 2;
    float* Hrow = ws;  ws += (size_t)N * HID;
    float* Hcol = ws;  ws += (size_t)N * HID;
    int* wi = (int*)ws;
    int* cnti = wi;  wi += N;
    int* basei = wi; wi += N;
    int* fill = wi;  wi += N;
    int* srow = wi;  wi += E;
    int* scol = wi;  wi += E;
    unsigned short* us = (unsigned short*)wi;
    unsigned short* w2p  = us;  us += 4 * 32768;
    unsigned short* c1p  = us;  us += 4 * 32768;
    unsigned short* v1p  = us;  us += 4 * 32768;
    unsigned short* n1ap = us;  us += 4 * 32768;
    unsigned short* n1bp = us;  us += 4 * 32768;
    unsigned short* n2p  = us;  us += 4 * 32768;
    unsigned short* hrp  = us;  us += 4 * 32768;
    unsigned short* hcp  = us;  us += 4 * 32768;
    float* outp = (float*)d_out;

    hipMemcpyAsync(xb, x_in, (size_t)N * 3 * sizeof(float), hipMemcpyDeviceToDevice, stream);
    hipMemcpyAsync(vb, v_in, (size_t)N * 3 * sizeof(float), hipMemcpyDeviceToDevice, stream);
    hipMemsetAsync(cnti, 0, 2 * N * sizeof(int), stream);  // cnti+basei; fill separate
    hipMemsetAsync(fill, 0, N * sizeof(int), stream);
    hipMemsetAsync(aggh, 0, (size_t)N * HID * sizeof(float), stream);  // layer 0 only;
    hipMemsetAsync(aggx, 0, (size_t)N * 3 * sizeof(float), stream);    // k_node re-zeroes
    k_cnt<<<(E + 255) / 256, 256, 0, stream>>>(rows, cnti, E);
    k_scan<<<1, 256, 0, stream>>>(cnti, basei, N);
    k_scatter<<<(E + 255) / 256, 256, 0, stream>>>(rows, cols, eattr, basei, fill,
                                                   srow, scol, sea, E);
    k_pack_w<<<(4 * 32768 + 255) / 256, 256, 0, stream>>>(ew2, cw1, w2p, c1p);
    k_pack_node<<<(4 * 6 * 16384 + 255) / 256, 256, 0, stream>>>(
        vw1, nw1, nw2, ew1, v1p, n1ap, n1bp, n2p, hrp, hcp);
    k_embed_hpre<<<(N + 63) / 64, 256, 0, stream>>>(h_in, emb_w, emb_b, ew1, eb1,
                                                    hbuf, Hrow, Hcol, N);

    for (int l = 0; l < 4; ++l) {
        k_edge_mfma<<<(E + 31) / 32, 256, 0, stream>>>(
            Hrow, Hcol, xb, srow, scol, sea,
            ew1 + (size_t)l * 33152 + 256 * HID,
            w2p + (size_t)l * 32768, eb2 + l * HID,
            aw + l * HID, ab + l,
            c1p + (size_t)l * 32768, cb1 + l * HID, cw2 + l * HID,
            aggh, aggx, E);
        int nl = l + 1;
        k_node_mfma<<<(N + 15) / 16, 256, 0, stream>>>(
            hbuf, aggh, aggx, cnti, xb, vb,
            v1p + (size_t)l * 32768, vb1 + l * HID, vw2 + l * HID, vb2 + l,
            n1ap + (size_t)l * 32768, n1bp + (size_t)l * 32768, nb1 + l * HID,
            n2p + (size_t)l * 32768, nb2 + l * HID,
            hrp + (size_t)(l < 3 ? nl : 0) * 32768,
            hcp + (size_t)(l < 3 ? nl : 0) * 32768,
            eb1 + (size_t)(l < 3 ? nl : 0) * HID,
            Hrow, Hcol, pw, pb, outp, N, (l == 3) ? 1 : 0);
    }
    hipMemcpyAsync(outp + (size_t)N * 3, xb, (size_t)N * 3 * sizeof(float), hipMemcpyDeviceToDevice, stream);
    hipMemcpyAsync(outp + (size_t)N * 6, vb, (size_t)N * 3 * sizeof(float), hipMemcpyDeviceToDevice, stream);
}